// Round 10
// baseline (622.060 us; speedup 1.0000x reference)
//
#include <hip/hip_runtime.h>
#include <hip/hip_bf16.h>
#include <cstddef>

typedef short bf16x8 __attribute__((ext_vector_type(8)));
typedef float f32x4 __attribute__((ext_vector_type(4)));

__device__ __forceinline__ unsigned short f2bf(float x) {
  __hip_bfloat16 h = __float2bfloat16(x);
  unsigned short u; __builtin_memcpy(&u, &h, 2); return u;
}
__device__ __forceinline__ float swz16f(float x) {   // lane ^= 16 (within 32-group)
  int i; __builtin_memcpy(&i, &x, 4);
  i = __builtin_amdgcn_ds_swizzle(i, 0x401F);
  float r; __builtin_memcpy(&r, &i, 4); return r;
}
__device__ __forceinline__ void gload16(const unsigned short* g, unsigned short* l) {
  __builtin_amdgcn_global_load_lds(
      (const __attribute__((address_space(1))) void*)g,
      (__attribute__((address_space(3))) void*)l, 16, 0, 0);
}
__device__ __forceinline__ void pipe_sync() {
  asm volatile("s_waitcnt vmcnt(0)" ::: "memory");
  __builtin_amdgcn_s_barrier();
  __builtin_amdgcn_sched_barrier(0);
}

// ---------------- all weights fp32 -> bf16 (contiguous dst) ----------------
__global__ __launch_bounds__(256) void cvt_all(
    const float* __restrict__ qkv_w, const float* __restrict__ out_w,
    const float* __restrict__ fc1_w, const float* __restrict__ fc2_w,
    const float* __restrict__ outp_w, unsigned short* __restrict__ dst)
{
  int i = blockIdx.x * 256 + threadIdx.x;
  if (i >= 1576960) return;
  const float* src; int off;
  if (i < 786432)       { src = qkv_w;  off = i; }
  else if (i < 1048576) { src = out_w;  off = i - 786432; }
  else if (i < 1310720) { src = fc1_w;  off = i - 1048576; }
  else if (i < 1572864) { src = fc2_w;  off = i - 1310720; }
  else                  { src = outp_w; off = i - 1572864; }
  float4 v = *(const float4*)(src + (size_t)off * 4);
  ushort4 o;
  o.x = f2bf(v.x); o.y = f2bf(v.y); o.z = f2bf(v.z); o.w = f2bf(v.w);
  *(ushort4*)(dst + (size_t)i * 4) = o;
}

// ---------------- conv1d (circular, k=3) + positional embedding ----------------
__global__ __launch_bounds__(256) void conv_pe_kernel(
    const float* __restrict__ x, const float* __restrict__ cw,
    const float* __restrict__ cb,
    float* __restrict__ outf, unsigned short* __restrict__ outb)
{
  const int L = 2048, CIN = 32;
  int b  = blockIdx.x >> 8;
  int l0 = (blockIdx.x & 255) << 3;
  int t  = threadIdx.x;
  __shared__ float xs[10][32];
  for (int idx = t; idx < 320; idx += 256) {
    int rr = idx >> 5, ci = idx & 31;
    int gl = (l0 - 1 + rr + L) & (L - 1);
    xs[rr][ci] = x[((size_t)b * L + gl) * CIN + ci];
  }
  __syncthreads();
  int e0 = t << 1;
  float acc0[8], acc1[8];
  float bb0 = cb[e0], bb1 = cb[e0 + 1];
#pragma unroll
  for (int li = 0; li < 8; li++) { acc0[li] = bb0; acc1[li] = bb1; }
  const float* w0p = cw + (size_t)e0 * 96;
  const float* w1p = w0p + 96;
  for (int ci = 0; ci < 32; ci++) {
#pragma unroll
    for (int kk = 0; kk < 3; kk++) {
      float w0 = w0p[ci * 3 + kk];
      float w1 = w1p[ci * 3 + kk];
#pragma unroll
      for (int li = 0; li < 8; li++) {
        float xv = xs[li + kk][ci];
        acc0[li] += xv * w0;
        acc1[li] += xv * w1;
      }
    }
  }
  float dv = __expf((float)e0 * (-9.210340371976184f / 512.0f));
#pragma unroll
  for (int li = 0; li < 8; li++) {
    int l = l0 + li;
    float arg = (float)l * dv;
    float sv = sinf(arg), cv = cosf(arg);
    float2 o; o.x = acc0[li] + sv; o.y = acc1[li] + cv;
    size_t off = ((size_t)b * L + l) * 512 + e0;
    *(float2*)&outf[off] = o;
    ushort2 ob; ob.x = f2bf(o.x); ob.y = f2bf(o.y);
    *(ushort2*)&outb[off] = ob;
  }
}

// ---------------- bf16 MFMA GEMM, 2-phase pipelined ----------------
// Y[M,N] = X[M,512] @ W[N,512]^T + bias.  Tile 128 x (NFR*32).
// EPI 0: Yb bf16 (QSCALE: cols<512 prescaled).  EPI 1: Yf f32 = +R.
// EPI 2: SiLU->Yb.  EPI 3: Yf f32 (no residual).
// VOUT: n-blocks with n0>=1024 write TRANSPOSED into VT[32][64][2048] (V path).
template<int EPI, int QSCALE, int NFR, int VOUT>
__global__ __launch_bounds__(256) void gemm_bf(
    const unsigned short* __restrict__ X,
    const unsigned short* __restrict__ W,
    const float* __restrict__ bias,
    const float* __restrict__ R,
    unsigned short* __restrict__ Yb,
    float* __restrict__ Yf,
    unsigned short* __restrict__ VT,
    int N)
{
  const int K = 512;
  constexpr int BN = NFR * 32;
  constexpr int WB = NFR * 4096;          // W-region bytes per buffer
  constexpr int BUF = 16384 + WB;
  __shared__ __align__(16) char smem[2 * BUF];
  int t = threadIdx.x;
  int lane = t & 63, wv = t >> 6;
  int g = lane >> 4, li = lane & 15;
  int m0 = (blockIdx.x & 63) << 7;
  int n0 = (blockIdx.x >> 6) * BN;
  int wm = (wv >> 1) << 6;
  int wn = (wv & 1) * (BN / 2);

  int subrow = lane >> 3;
  int coloff = ((lane & 7) ^ subrow) << 3;   // inverse swizzle on global source

  f32x4 acc[4][NFR];
#pragma unroll
  for (int a = 0; a < 4; a++)
#pragma unroll
    for (int b2 = 0; b2 < NFR; b2++) acc[a][b2] = (f32x4){0.f, 0.f, 0.f, 0.f};

  // prologue: stage k-step 0 into buf 0
#pragma unroll
  for (int j = 0; j < 4; j++) {
    int row = (wv * 4 + j) * 8 + subrow;
    gload16(X + (size_t)(m0 + row) * K + coloff,
            (unsigned short*)(smem + (wv * 4 + j) * 1024));
  }
#pragma unroll
  for (int j = 0; j < NFR; j++) {
    int row = (wv * NFR + j) * 8 + subrow;
    gload16(W + (size_t)(n0 + row) * K + coloff,
            (unsigned short*)(smem + 16384 + (wv * NFR + j) * 1024));
  }
  pipe_sync();

#pragma unroll
  for (int ks = 0; ks < 8; ks++) {
    const int buf = ks & 1;
    char* cur = smem + buf * BUF;
    if (ks < 7) {                     // issue next-tile loads first
      char* nxt = smem + (buf ^ 1) * BUF;
      int k0 = (ks + 1) * 64;
#pragma unroll
      for (int j = 0; j < 4; j++) {
        int row = (wv * 4 + j) * 8 + subrow;
        gload16(X + (size_t)(m0 + row) * K + k0 + coloff,
                (unsigned short*)(nxt + (wv * 4 + j) * 1024));
      }
#pragma unroll
      for (int j = 0; j < NFR; j++) {
        int row = (wv * NFR + j) * 8 + subrow;
        gload16(W + (size_t)(n0 + row) * K + k0 + coloff,
                (unsigned short*)(nxt + 16384 + (wv * NFR + j) * 1024));
      }
    }
#pragma unroll
    for (int s = 0; s < 2; s++) {
      bf16x8 af[4], bfr[NFR];
#pragma unroll
      for (int mt = 0; mt < 4; mt++) {
        int row = wm + 16 * mt + li;
        af[mt] = *(const bf16x8*)(cur + (row * 8 + ((g + 4 * s) ^ (row & 7))) * 16);
      }
#pragma unroll
      for (int nt = 0; nt < NFR; nt++) {
        int row = wn + 16 * nt + li;
        bfr[nt] = *(const bf16x8*)(cur + 16384 +
                                   (row * 8 + ((g + 4 * s) ^ (row & 7))) * 16);
      }
#pragma unroll
      for (int mt = 0; mt < 4; mt++)
#pragma unroll
        for (int nt = 0; nt < NFR; nt++)
          acc[mt][nt] = __builtin_amdgcn_mfma_f32_16x16x32_bf16(
              af[mt], bfr[nt], acc[mt][nt], 0, 0, 0);
    }
    pipe_sync();
  }

  float bv[NFR];
#pragma unroll
  for (int nt = 0; nt < NFR; nt++) bv[nt] = bias[n0 + wn + 16 * nt + li];

  if (VOUT && n0 >= 1024) {
    // transposed V output: LDS bounce (rows = tile cols, stride 136 shorts)
    unsigned short* Ts = (unsigned short*)smem;
#pragma unroll
    for (int nt = 0; nt < NFR; nt++) {
      int col = wn + 16 * nt + li;
      float bvn = bv[nt];
#pragma unroll
      for (int mt = 0; mt < 4; mt++) {
        float v0 = acc[mt][nt][0] + bvn, v1 = acc[mt][nt][1] + bvn;
        float v2 = acc[mt][nt][2] + bvn, v3 = acc[mt][nt][3] + bvn;
        uint2 pk;
        asm("v_cvt_pk_bf16_f32 %0, %1, %2" : "=v"(pk.x) : "v"(v0), "v"(v1));
        asm("v_cvt_pk_bf16_f32 %0, %1, %2" : "=v"(pk.y) : "v"(v2), "v"(v3));
        *(uint2*)(Ts + col * 136 + wm + 16 * mt + 4 * g) = pk;
      }
    }
    __syncthreads();
    int vcol = t >> 1, half = t & 1;
    int gc = n0 - 1024 + vcol;
    int bh = (m0 >> 11) * 8 + (gc >> 6);
    int d  = gc & 63;
    unsigned short* dst = VT + ((size_t)bh * 64 + d) * 2048 + (m0 & 2047) + half * 64;
    const unsigned short* srcp = Ts + vcol * 136 + half * 64;
#pragma unroll
    for (int j2 = 0; j2 < 8; j2++)
      *(bf16x8*)(dst + j2 * 8) = *(const bf16x8*)(srcp + j2 * 8);
    return;
  }

#pragma unroll
  for (int mt = 0; mt < 4; mt++) {
#pragma unroll
    for (int i = 0; i < 4; i++) {
      size_t roff = (size_t)(m0 + wm + 16 * mt + 4 * g + i) * N;
#pragma unroll
      for (int nt = 0; nt < NFR; nt++) {
        int col = n0 + wn + 16 * nt + li;
        float v = acc[mt][nt][i] + bv[nt];
        if (EPI == 1) {
          v += R[roff + col];
          Yf[roff + col] = v;
        } else if (EPI == 2) {
          v = v / (1.f + __expf(-v));
          Yb[roff + col] = f2bf(v);
        } else if (EPI == 3) {
          Yf[roff + col] = v;
        } else {
          if (QSCALE && col < 512) v *= 0.18033688011112042f;  // 0.125*log2(e)
          Yb[roff + col] = f2bf(v);
        }
      }
    }
  }
}

// ---------------- MFMA flash attention, 2-phase pipelined, KVBLK=128 ----------
// QBLK=128; grid 512: bh = bid&31 (XCD-local), qi = bid>>5; 4 waves; Q prescaled.
__global__ __launch_bounds__(256) void attn_mfma(
    const unsigned short* __restrict__ qkv,  // [8192,1536] bf16
    const unsigned short* __restrict__ Vt,   // [32,64,2048] bf16
    unsigned short* __restrict__ ctx)        // [8192,512] bf16
{
  const int L = 2048;
  int bh = blockIdx.x & 31, qi = blockIdx.x >> 5;   // same-bh blocks -> same XCD
  int b = bh >> 3, h = bh & 7;
  int q0 = qi << 7;
  size_t tb = (size_t)b * L;
  int t = threadIdx.x, lane = t & 63, wv = t >> 6;
  int g = lane >> 4, li = lane & 15;
  int lisw = li & 7;

  // smem: buf{0,1}: [K 16K | V 16K] at 0/32768 ; P 16K at 65536 (4K/wave)
  __shared__ __align__(16) char smem[81920];

  const f32x4 kZero = {0.f, 0.f, 0.f, 0.f};
  bf16x8 ones;
#pragma unroll
  for (int j = 0; j < 8; j++) ones[j] = (short)0x3F80;   // bf16 1.0

  int wq = q0 + wv * 32;
  bf16x8 qf00, qf01, qf10, qf11;
  {
    const unsigned short* qp0 = qkv + (tb + wq + li) * 1536 + h * 64 + g * 8;
    qf00 = *(const bf16x8*)qp0;
    qf01 = *(const bf16x8*)(qp0 + 32);
    const unsigned short* qp1 = qp0 + (size_t)16 * 1536;
    qf10 = *(const bf16x8*)qp1;
    qf11 = *(const bf16x8*)(qp1 + 32);
  }

  f32x4 accA[4], accB[4], accLA, accLB;
#pragma unroll
  for (int nt = 0; nt < 4; nt++) {
    accA[nt] = kZero;
    accB[nt] = kZero;
  }
  accLA = kZero; accLB = kZero;
  float mA = -1e30f, mB = -1e30f;

  // K fragment offsets (K region rows = 128B): row = 16mt+li
  int koff0 = li * 128 + ((g    ) ^ lisw) * 16;
  int koff1 = li * 128 + ((g + 4) ^ lisw) * 16;
  // V fragment offsets (V region rows = 256B, 16 slots): row = 16nt+li
  int vrowb = 16384 + li * 256;
  int vs00 = ((g    ) ^ lisw) << 4;     // pass 0, d-half 0
  int vs01 = ((g + 4) ^ lisw) << 4;     // pass 0, d-half 1
  int vs10 = ((8 + g) ^ lisw) << 4;     // pass 1, d-half 0
  int vs11 = ((12 + g) ^ lisw) << 4;    // pass 1, d-half 1
  // P pointers (wave-private 4KB at 65536)
  const char* pb0 = smem + 65536 + wv * 4096 + li * 128 + ((g    ) ^ lisw) * 16;
  const char* pb1 = smem + 65536 + wv * 4096 + li * 128 + ((g + 4) ^ lisw) * 16;
  char* pwbase = smem + 65536 + wv * 4096 + li * 128 + ((g & 1) << 3);
  char* pw0 = pwbase + (((0 + (g >> 1)) ^ lisw) << 4);
  char* pw1 = pwbase + (((2 + (g >> 1)) ^ lisw) << 4);
  char* pw2 = pwbase + (((4 + (g >> 1)) ^ lisw) << 4);
  char* pw3 = pwbase + (((6 + (g >> 1)) ^ lisw) << 4);

  // staging pointers: K 4 issues (rows 0..127), V 4 issues (rows 0..63)
  int subrow = lane >> 3;
  int coloff = ((lane & 7) ^ subrow) << 3;
  const unsigned short* kp[4];
  const unsigned short* vp[4];
#pragma unroll
  for (int j = 0; j < 4; j++) {
    int krow = (wv * 4 + j) * 8 + subrow;
    kp[j] = qkv + (tb + krow) * 1536 + 512 + h * 64 + coloff;
    int vrow = (wv * 4 + j) * 4 + g;
    vp[j] = Vt + ((size_t)bh * 64 + vrow) * 2048 + ((li ^ (vrow & 7)) << 3);
  }

  // prologue: stage tile 0 into buf 0
#pragma unroll
  for (int j = 0; j < 4; j++) {
    gload16(kp[j], (unsigned short*)(smem + (wv * 4 + j) * 1024));
    gload16(vp[j], (unsigned short*)(smem + 16384 + (wv * 4 + j) * 1024));
    kp[j] += (size_t)128 * 1536; vp[j] += 128;
  }
  pipe_sync();

#pragma unroll 2
  for (int it = 0; it < 16; it++) {
    const int buf = it & 1;
    const char* base = smem + buf * 32768;
    if (it < 15) {                    // issue next tile first (latency hides)
      char* nb = smem + (buf ^ 1) * 32768;
#pragma unroll
      for (int j = 0; j < 4; j++) {
        gload16(kp[j], (unsigned short*)(nb + (wv * 4 + j) * 1024));
        gload16(vp[j], (unsigned short*)(nb + 16384 + (wv * 4 + j) * 1024));
        kp[j] += (size_t)128 * 1536; vp[j] += 128;
      }
    }

    // S^T = K . Q^T over 128 keys; first d-half inits from kZero (no v_movs)
    f32x4 sA[8], sB[8];
    __builtin_amdgcn_s_setprio(1);
#pragma unroll
    for (int mt = 0; mt < 8; mt++) {
      bf16x8 kf = *(const bf16x8*)(base + koff0 + mt * 2048);
      sA[mt] = __builtin_amdgcn_mfma_f32_16x16x32_bf16(kf, qf00, kZero, 0, 0, 0);
      sB[mt] = __builtin_amdgcn_mfma_f32_16x16x32_bf16(kf, qf10, kZero, 0, 0, 0);
    }
#pragma unroll
    for (int mt = 0; mt < 8; mt++) {
      bf16x8 kf = *(const bf16x8*)(base + koff1 + mt * 2048);
      sA[mt] = __builtin_amdgcn_mfma_f32_16x16x32_bf16(kf, qf01, sA[mt], 0, 0, 0);
      sB[mt] = __builtin_amdgcn_mfma_f32_16x16x32_bf16(kf, qf11, sB[mt], 0, 0, 0);
    }
    __builtin_amdgcn_s_setprio(0);

    // tile maxes over 128 keys
    float mxA = -1e30f, mxB = -1e30f;
#pragma unroll
    for (int mt = 0; mt < 8; mt++) {
      mxA = fmaxf(mxA, fmaxf(fmaxf(sA[mt][0], sA[mt][1]), fmaxf(sA[mt][2], sA[mt][3])));
      mxB = fmaxf(mxB, fmaxf(fmaxf(sB[mt][0], sB[mt][1]), fmaxf(sB[mt][2], sB[mt][3])));
    }
    mxA = fmaxf(mxA, swz16f(mxA)); mxA = fmaxf(mxA, __shfl_xor(mxA, 32));
    mxB = fmaxf(mxB, swz16f(mxB)); mxB = fmaxf(mxB, __shfl_xor(mxB, 32));

    // defer-max (THR=8, exp2 domain)
    if (__any((mxA > mA + 8.0f) || (mxB > mB + 8.0f))) {
      float mnA = fmaxf(mA, mxA), mnB = fmaxf(mB, mxB);
      float cA = mA - mnA, cB = mB - mnB;
      asm volatile("v_exp_f32 %0, %0\n\tv_exp_f32 %1, %1\n\ts_nop 1"
                   : "+v"(cA), "+v"(cB));
      float c0 = __shfl(cA, 4 * g + 0), c1 = __shfl(cA, 4 * g + 1);
      float c2 = __shfl(cA, 4 * g + 2), c3 = __shfl(cA, 4 * g + 3);
#pragma unroll
      for (int nt = 0; nt < 4; nt++) {
        accA[nt][0] *= c0; accA[nt][1] *= c1;
        accA[nt][2] *= c2; accA[nt][3] *= c3;
      }
      accLA[0] *= c0; accLA[1] *= c1; accLA[2] *= c2; accLA[3] *= c3;
      float d0 = __shfl(cB, 4 * g + 0), d1 = __shfl(cB, 4 * g + 1);
      float d2 = __shfl(cB, 4 * g + 2), d3 = __shfl(cB, 4 * g + 3);
#pragma unroll
      for (int nt = 0; nt < 4; nt++) {
        accB[nt][0] *= d0; accB[nt][1] *= d1;
        accB[nt][2] *= d2; accB[nt][3] *= d3;
      }
      accLB[0] *= d0; accLB[1] *= d1; accLB[2] *= d2; accLB[3] *= d3;
      mA = mnA; mB = mnB;
    }

#define PBLK(SARR, MM, PWP, OFF)                                              \
    {                                                                         \
      float p0 = SARR[0] - MM, p1 = SARR[1] - MM,                             \
            p2 = SARR[2] - MM, p3 = SARR[3] - MM;                             \
      asm volatile("v_exp_f32 %0, %0\n\tv_exp_f32 %1, %1\n\t"                 \
                   "v_exp_f32 %2, %2\n\tv_exp_f32 %3, %3\n\ts_nop 1"          \
                   : "+v"(p0), "+v"(p1), "+v"(p2), "+v"(p3));                 \
      uint2 pv;                                                               \
      asm("v_cvt_pk_bf16_f32 %0, %1, %2" : "=v"(pv.x) : "v"(p0), "v"(p1));    \
      asm("v_cvt_pk_bf16_f32 %0, %1, %2" : "=v"(pv.y) : "v"(p2), "v"(p3));    \
      *(uint2*)(PWP + OFF) = pv;                                              \
    }
    // ---- pass 0: keys 0..63 ----
    PBLK(sA[0], mA, pw0, 0) PBLK(sA[1], mA, pw1, 0)
    PBLK(sA[2], mA, pw2, 0) PBLK(sA[3], mA, pw3, 0)
    PBLK(sB[0], mB, pw0, 2048) PBLK(sB[1], mB, pw1, 2048)
    PBLK(sB[2], mB, pw2, 2048) PBLK(sB[3], mB, pw3, 2048)
    {
      bf16x8 paA0 = *(const bf16x8*)(pb0);
      bf16x8 paB0 = *(const bf16x8*)(pb0 + 2048);
      bf16x8 paA1 = *(const bf16x8*)(pb1);
      bf16x8 paB1 = *(const bf16x8*)(pb1 + 2048);
      __builtin_amdgcn_s_setprio(1);
#pragma unroll
      for (int nt = 0; nt < 4; nt++) {
        bf16x8 vb = *(const bf16x8*)(base + vrowb + nt * 4096 + vs00);
        accA[nt] = __builtin_amdgcn_mfma_f32_16x16x32_bf16(paA0, vb, accA[nt], 0, 0, 0);
        accB[nt] = __builtin_amdgcn_mfma_f32_16x16x32_bf16(paB0, vb, accB[nt], 0, 0, 0);
      }
#pragma unroll
      for (int nt = 0; nt < 4; nt++) {
        bf16x8 vb = *(const bf16x8*)(base + vrowb + nt * 4096 + vs01);
        accA[nt] = __builtin_amdgcn_mfma_f32_16x16x32_bf16(paA1, vb, accA[nt], 0, 0, 0);
        accB[nt] = __builtin_amdgcn_mfma_f32_16x16x32_bf16(paB1, vb, accB[nt], 0, 0, 0);
      }
      accLA = __builtin_amdgcn_mfma_f32_16x16x32_bf16(paA0, ones, accLA, 0, 0, 0);
      accLA = __builtin_amdgcn_mfma_f32_16x16x32_bf16(paA1, ones, accLA, 0, 0, 0);
      accLB = __builtin_amdgcn_mfma_f32_16x16x32_bf16(paB0, ones, accLB, 0, 0, 0);
      accLB = __builtin_amdgcn_mfma_f32_16x16x32_bf16(paB1, ones, accLB, 0, 0, 0);
      __builtin_amdgcn_s_setprio(0);
    }
    // ---- pass 1: keys 64..127 (reuse wave-private P buffer) ----
    PBLK(sA[4], mA, pw0, 0) PBLK(sA[5], mA, pw1, 0)
    PBLK(sA[6], mA, pw2, 0) PBLK(sA[7], mA, pw3, 0)
    PBLK(sB[4], mB, pw0, 2048) PBLK(sB[5], mB, pw1, 2048)
    PBLK(sB[6], mB, pw2, 2048) PBLK(sB[7], mB, pw3, 2048)
#undef PBLK
    {
      bf16x8 paA0 = *(const bf16x8*)(pb0);
      bf16x8 paB0 = *(const bf16x8*)(pb0 + 2048);
      bf16x8 paA1 = *(const bf16x8*)(pb1);
      bf16x8 paB1 = *(const bf16x8*)(pb1 + 2048);
      __builtin_amdgcn_s_setprio(1);
#pragma unroll
      for (int nt = 0; nt < 4; nt++) {
        bf16x8 vb = *(const bf16x8*)(base + vrowb + nt * 4096 + vs10);
        accA[nt] = __builtin_amdgcn_mfma_f32_16x16x32_bf16(paA0, vb, accA[nt], 0, 0, 0);
        accB[nt] = __builtin_amdgcn_mfma_f32_16x16x32_bf16(paB0, vb, accB[nt], 0, 0, 0);
      }
#pragma unroll
      for (int nt = 0; nt < 4; nt++) {
        bf16x8 vb = *(const bf16x8*)(base + vrowb + nt * 4096 + vs11);
        accA[nt] = __builtin_amdgcn_mfma_f32_16x16x32_bf16(paA1, vb, accA[nt], 0, 0, 0);
        accB[nt] = __builtin_amdgcn_mfma_f32_16x16x32_bf16(paB1, vb, accB[nt], 0, 0, 0);
      }
      accLA = __builtin_amdgcn_mfma_f32_16x16x32_bf16(paA0, ones, accLA, 0, 0, 0);
      accLA = __builtin_amdgcn_mfma_f32_16x16x32_bf16(paA1, ones, accLA, 0, 0, 0);
      accLB = __builtin_amdgcn_mfma_f32_16x16x32_bf16(paB0, ones, accLB, 0, 0, 0);
      accLB = __builtin_amdgcn_mfma_f32_16x16x32_bf16(paB1, ones, accLB, 0, 0, 0);
      __builtin_amdgcn_s_setprio(0);
    }

    pipe_sync();
  }

  // l is in accL (rowsum over all keys, same bf16 P as numerator); no shfl.
  float liA[4], liB[4];
#pragma unroll
  for (int i = 0; i < 4; i++) {
    liA[i] = 1.f / accLA[i];
    liB[i] = 1.f / accLB[i];
  }
#pragma unroll
  for (int i = 0; i < 4; i++) {
    size_t ra = (tb + wq + 4 * g + i) * 512 + h * 64;
    size_t rb = (tb + wq + 16 + 4 * g + i) * 512 + h * 64;
#pragma unroll
    for (int nt = 0; nt < 4; nt++) {
      ctx[ra + 16 * nt + li] = f2bf(accA[nt][i] * liA[i]);
      ctx[rb + 16 * nt + li] = f2bf(accB[nt][i] * liB[i]);
    }
  }
}

// ---------------- LayerNorm over E=512; one wave per row; f32 + bf16 out ------
__global__ __launch_bounds__(256) void ln_kernel(
    const float* __restrict__ X, const float* __restrict__ g,
    const float* __restrict__ b, float* __restrict__ Yf,
    unsigned short* __restrict__ Yb)
{
  int t = threadIdx.x, lane = t & 63, wv = t >> 6;
  size_t row = (size_t)blockIdx.x * 4 + wv;
  const float* xp = X + row * 512 + lane * 8;
  float4 a = *(const float4*)xp;
  float4 c = *(const float4*)(xp + 4);
  float sum = a.x + a.y + a.z + a.w + c.x + c.y + c.z + c.w;
  float sq  = a.x*a.x + a.y*a.y + a.z*a.z + a.w*a.w
            + c.x*c.x + c.y*c.y + c.z*c.z + c.w*c.w;
#pragma unroll
  for (int off = 32; off > 0; off >>= 1) {
    sum += __shfl_xor(sum, off);
    sq  += __shfl_xor(sq, off);
  }
  float mu  = sum * (1.0f / 512.0f);
  float inv = rsqrtf(sq * (1.0f / 512.0f) - mu * mu + 1e-5f);
  float4 g0 = *(const float4*)(g + lane * 8);
  float4 g1 = *(const float4*)(g + lane * 8 + 4);
  float4 b0 = *(const float4*)(b + lane * 8);
  float4 b1 = *(const float4*)(b + lane * 8 + 4);
  float y[8];
  y[0] = (a.x - mu) * inv * g0.x + b0.x;
  y[1] = (a.y - mu) * inv * g0.y + b0.y;
  y[2] = (a.z - mu) * inv * g0.z + b0.z;
  y[3] = (a.w - mu) * inv * g0.w + b0.w;
  y[4] = (c.x - mu) * inv * g1.x + b1.x;
  y[5] = (c.y - mu) * inv * g1.y + b1.y;
  y[6] = (c.z - mu) * inv * g1.z + b1.z;
  y[7] = (c.w - mu) * inv * g1.w + b1.w;
  float4 y0 = {y[0], y[1], y[2], y[3]};
  float4 y1 = {y[4], y[5], y[6], y[7]};
  *(float4*)(Yf + row * 512 + lane * 8)     = y0;
  *(float4*)(Yf + row * 512 + lane * 8 + 4) = y1;
  bf16x8 yb;
#pragma unroll
  for (int j = 0; j < 8; j++) yb[j] = (short)f2bf(y[j]);
  *(bf16x8*)(Yb + row * 512 + lane * 8) = yb;
}

extern "C" void kernel_launch(void* const* d_in, const int* in_sizes, int n_in,
                              void* d_out, int out_size, void* d_ws, size_t ws_size,
                              hipStream_t stream) {
  (void)in_sizes; (void)n_in; (void)out_size; (void)ws_size;
  const float* x      = (const float*)d_in[0];
  const float* conv_w = (const float*)d_in[1];
  const float* conv_b = (const float*)d_in[2];
  const float* qkv_w  = (const float*)d_in[3];
  const float* qkv_b  = (const float*)d_in[4];
  const float* out_w  = (const float*)d_in[5];
  const float* out_b  = (const float*)d_in[6];
  const float* fc1_w  = (const float*)d_in[7];
  const float* fc1_b  = (const float*)d_in[8];
  const float* fc2_w  = (const float*)d_in[9];
  const float* fc2_b  = (const float*)d_in[10];
  const float* ln1_w  = (const float*)d_in[11];
  const float* ln1_b  = (const float*)d_in[12];
  const float* ln2_w  = (const float*)d_in[13];
  const float* ln2_b  = (const float*)d_in[14];
  const float* outp_w = (const float*)d_in[15];
  const float* outp_b = (const float*)d_in[16];
  float* out = (float*)d_out;

  char* p = (char*)d_ws;
  unsigned short* A_bf = (unsigned short*)p;            p += (size_t)8192 * 512 * 2;
  float*          A_f  = (float*)p;                     p += (size_t)8192 * 512 * 4;
  unsigned short* QKV  = (unsigned short*)p;            p += (size_t)8192 * 1536 * 2;
  unsigned short* VT   = (unsigned short*)p;            p += (size_t)32 * 64 * 2048 * 2;
  unsigned short* CTX  = (unsigned short*)p;            p += (size_t)8192 * 512 * 2;
  unsigned short* Wq   = (unsigned short*)p;            p += (size_t)4 * 1536 * 512 * 2;
  unsigned short* Wo   = (unsigned short*)p;            p += (size_t)4 * 512 * 512 * 2;
  unsigned short* W1   = (unsigned short*)p;            p += (size_t)4 * 512 * 512 * 2;
  unsigned short* W2   = (unsigned short*)p;            p += (size_t)4 * 512 * 512 * 2;
  unsigned short* Wp   = (unsigned short*)p;            p += (size_t)32 * 512 * 2;
  float* D = (float*)QKV;   // aliased: D[8192,512] f32 in QKV region (disjoint lifetime)

  cvt_all<<<6160, 256, 0, stream>>>(qkv_w, out_w, fc1_w, fc2_w, outp_w, Wq);

  conv_pe_kernel<<<1024, 256, 0, stream>>>(x, conv_w, conv_b, A_f, A_bf);

  for (int l = 0; l < 4; l++) {
    gemm_bf<0, 1, 4, 1><<<64 * 12, 256, 0, stream>>>(
        A_bf, Wq + (size_t)l * 1536 * 512, qkv_b + l * 1536, nullptr,
        QKV, nullptr, VT, 1536);
    attn_mfma<<<512, 256, 0, stream>>>(QKV, VT, CTX);
    gemm_bf<1, 0, 2, 0><<<64 * 8, 256, 0, stream>>>(
        CTX, Wo + (size_t)l * 512 * 512, out_b + l * 512, A_f,
        nullptr, D, nullptr, 512);
    ln_kernel<<<2048, 256, 0, stream>>>(D, ln1_w + l * 512, ln1_b + l * 512, A_f, A_bf);
    gemm_bf<2, 0, 2, 0><<<64 * 8, 256, 0, stream>>>(
        A_bf, W1 + (size_t)l * 512 * 512, fc1_b + l * 512, nullptr,
        CTX, nullptr, nullptr, 512);
    gemm_bf<1, 0, 2, 0><<<64 * 8, 256, 0, stream>>>(
        CTX, W2 + (size_t)l * 512 * 512, fc2_b + l * 512, A_f,
        nullptr, D, nullptr, 512);
    ln_kernel<<<2048, 256, 0, stream>>>(D, ln2_w + l * 512, ln2_b + l * 512, A_f, A_bf);
  }
  gemm_bf<3, 0, 1, 0><<<64, 256, 0, stream>>>(
      A_bf, Wp, outp_b, nullptr, nullptr, out, nullptr, 32);
}

// Round 11
// 567.853 us; speedup vs baseline: 1.0955x; 1.0955x over previous
//
#include <hip/hip_runtime.h>
#include <hip/hip_bf16.h>
#include <cstddef>

typedef short bf16x8 __attribute__((ext_vector_type(8)));
typedef float f32x4 __attribute__((ext_vector_type(4)));

__device__ __forceinline__ unsigned short f2bf(float x) {
  __hip_bfloat16 h = __float2bfloat16(x);
  unsigned short u; __builtin_memcpy(&u, &h, 2); return u;
}
__device__ __forceinline__ float swz16f(float x) {   // lane ^= 16 (within 32-group)
  int i; __builtin_memcpy(&i, &x, 4);
  i = __builtin_amdgcn_ds_swizzle(i, 0x401F);
  float r; __builtin_memcpy(&r, &i, 4); return r;
}
__device__ __forceinline__ void gload16(const unsigned short* g, unsigned short* l) {
  __builtin_amdgcn_global_load_lds(
      (const __attribute__((address_space(1))) void*)g,
      (__attribute__((address_space(3))) void*)l, 16, 0, 0);
}
__device__ __forceinline__ void pipe_sync() {
  asm volatile("s_waitcnt vmcnt(0)" ::: "memory");
  __builtin_amdgcn_s_barrier();
  __builtin_amdgcn_sched_barrier(0);
}

// ---------------- all weights fp32 -> bf16 (contiguous dst) ----------------
__global__ __launch_bounds__(256) void cvt_all(
    const float* __restrict__ qkv_w, const float* __restrict__ out_w,
    const float* __restrict__ fc1_w, const float* __restrict__ fc2_w,
    const float* __restrict__ outp_w, unsigned short* __restrict__ dst)
{
  int i = blockIdx.x * 256 + threadIdx.x;
  if (i >= 1576960) return;
  const float* src; int off;
  if (i < 786432)       { src = qkv_w;  off = i; }
  else if (i < 1048576) { src = out_w;  off = i - 786432; }
  else if (i < 1310720) { src = fc1_w;  off = i - 1048576; }
  else if (i < 1572864) { src = fc2_w;  off = i - 1310720; }
  else                  { src = outp_w; off = i - 1572864; }
  float4 v = *(const float4*)(src + (size_t)off * 4);
  ushort4 o;
  o.x = f2bf(v.x); o.y = f2bf(v.y); o.z = f2bf(v.z); o.w = f2bf(v.w);
  *(ushort4*)(dst + (size_t)i * 4) = o;
}

// ---------------- conv1d (circular, k=3) + positional embedding ----------------
__global__ __launch_bounds__(256) void conv_pe_kernel(
    const float* __restrict__ x, const float* __restrict__ cw,
    const float* __restrict__ cb,
    float* __restrict__ outf, unsigned short* __restrict__ outb)
{
  const int L = 2048, CIN = 32;
  int b  = blockIdx.x >> 8;
  int l0 = (blockIdx.x & 255) << 3;
  int t  = threadIdx.x;
  __shared__ float xs[10][32];
  for (int idx = t; idx < 320; idx += 256) {
    int rr = idx >> 5, ci = idx & 31;
    int gl = (l0 - 1 + rr + L) & (L - 1);
    xs[rr][ci] = x[((size_t)b * L + gl) * CIN + ci];
  }
  __syncthreads();
  int e0 = t << 1;
  float acc0[8], acc1[8];
  float bb0 = cb[e0], bb1 = cb[e0 + 1];
#pragma unroll
  for (int li = 0; li < 8; li++) { acc0[li] = bb0; acc1[li] = bb1; }
  const float* w0p = cw + (size_t)e0 * 96;
  const float* w1p = w0p + 96;
  for (int ci = 0; ci < 32; ci++) {
#pragma unroll
    for (int kk = 0; kk < 3; kk++) {
      float w0 = w0p[ci * 3 + kk];
      float w1 = w1p[ci * 3 + kk];
#pragma unroll
      for (int li = 0; li < 8; li++) {
        float xv = xs[li + kk][ci];
        acc0[li] += xv * w0;
        acc1[li] += xv * w1;
      }
    }
  }
  float dv = __expf((float)e0 * (-9.210340371976184f / 512.0f));
#pragma unroll
  for (int li = 0; li < 8; li++) {
    int l = l0 + li;
    float arg = (float)l * dv;
    float sv = sinf(arg), cv = cosf(arg);
    float2 o; o.x = acc0[li] + sv; o.y = acc1[li] + cv;
    size_t off = ((size_t)b * L + l) * 512 + e0;
    *(float2*)&outf[off] = o;
    ushort2 ob; ob.x = f2bf(o.x); ob.y = f2bf(o.y);
    *(ushort2*)&outb[off] = ob;
  }
}

// ---------------- bf16 MFMA GEMM, 2-phase pipelined ----------------
// Y[M,N] = X[M,512] @ W[N,512]^T + bias.  Tile 128 x (NFR*32).
// EPI 0: Yb bf16 (QSCALE: cols<512 prescaled).  EPI 1: Yf f32 = +R.
// EPI 2: SiLU->Yb.  EPI 3: Yf f32 (no residual).
// VOUT: n-blocks with n0>=1024 write TRANSPOSED into VT[32][64][2048] (V path).
template<int EPI, int QSCALE, int NFR, int VOUT>
__global__ __launch_bounds__(256) void gemm_bf(
    const unsigned short* __restrict__ X,
    const unsigned short* __restrict__ W,
    const float* __restrict__ bias,
    const float* __restrict__ R,
    unsigned short* __restrict__ Yb,
    float* __restrict__ Yf,
    unsigned short* __restrict__ VT,
    int N)
{
  const int K = 512;
  constexpr int BN = NFR * 32;
  constexpr int WB = NFR * 4096;          // W-region bytes per buffer
  constexpr int BUF = 16384 + WB;
  __shared__ __align__(16) char smem[2 * BUF];
  int t = threadIdx.x;
  int lane = t & 63, wv = t >> 6;
  int g = lane >> 4, li = lane & 15;
  int m0 = (blockIdx.x & 63) << 7;
  int n0 = (blockIdx.x >> 6) * BN;
  int wm = (wv >> 1) << 6;
  int wn = (wv & 1) * (BN / 2);

  int subrow = lane >> 3;
  int coloff = ((lane & 7) ^ subrow) << 3;   // inverse swizzle on global source

  f32x4 acc[4][NFR];
#pragma unroll
  for (int a = 0; a < 4; a++)
#pragma unroll
    for (int b2 = 0; b2 < NFR; b2++) acc[a][b2] = (f32x4){0.f, 0.f, 0.f, 0.f};

  // prologue: stage k-step 0 into buf 0
#pragma unroll
  for (int j = 0; j < 4; j++) {
    int row = (wv * 4 + j) * 8 + subrow;
    gload16(X + (size_t)(m0 + row) * K + coloff,
            (unsigned short*)(smem + (wv * 4 + j) * 1024));
  }
#pragma unroll
  for (int j = 0; j < NFR; j++) {
    int row = (wv * NFR + j) * 8 + subrow;
    gload16(W + (size_t)(n0 + row) * K + coloff,
            (unsigned short*)(smem + 16384 + (wv * NFR + j) * 1024));
  }
  pipe_sync();

#pragma unroll
  for (int ks = 0; ks < 8; ks++) {
    const int buf = ks & 1;
    char* cur = smem + buf * BUF;
    if (ks < 7) {                     // issue next-tile loads first
      char* nxt = smem + (buf ^ 1) * BUF;
      int k0 = (ks + 1) * 64;
#pragma unroll
      for (int j = 0; j < 4; j++) {
        int row = (wv * 4 + j) * 8 + subrow;
        gload16(X + (size_t)(m0 + row) * K + k0 + coloff,
                (unsigned short*)(nxt + (wv * 4 + j) * 1024));
      }
#pragma unroll
      for (int j = 0; j < NFR; j++) {
        int row = (wv * NFR + j) * 8 + subrow;
        gload16(W + (size_t)(n0 + row) * K + k0 + coloff,
                (unsigned short*)(nxt + 16384 + (wv * NFR + j) * 1024));
      }
    }
#pragma unroll
    for (int s = 0; s < 2; s++) {
      bf16x8 af[4], bfr[NFR];
#pragma unroll
      for (int mt = 0; mt < 4; mt++) {
        int row = wm + 16 * mt + li;
        af[mt] = *(const bf16x8*)(cur + (row * 8 + ((g + 4 * s) ^ (row & 7))) * 16);
      }
#pragma unroll
      for (int nt = 0; nt < NFR; nt++) {
        int row = wn + 16 * nt + li;
        bfr[nt] = *(const bf16x8*)(cur + 16384 +
                                   (row * 8 + ((g + 4 * s) ^ (row & 7))) * 16);
      }
#pragma unroll
      for (int mt = 0; mt < 4; mt++)
#pragma unroll
        for (int nt = 0; nt < NFR; nt++)
          acc[mt][nt] = __builtin_amdgcn_mfma_f32_16x16x32_bf16(
              af[mt], bfr[nt], acc[mt][nt], 0, 0, 0);
    }
    pipe_sync();
  }

  float bv[NFR];
#pragma unroll
  for (int nt = 0; nt < NFR; nt++) bv[nt] = bias[n0 + wn + 16 * nt + li];

  if (VOUT && n0 >= 1024) {
    // transposed V output: LDS bounce (rows = tile cols, stride 136 shorts)
    unsigned short* Ts = (unsigned short*)smem;
#pragma unroll
    for (int nt = 0; nt < NFR; nt++) {
      int col = wn + 16 * nt + li;
      float bvn = bv[nt];
#pragma unroll
      for (int mt = 0; mt < 4; mt++) {
        float v0 = acc[mt][nt][0] + bvn, v1 = acc[mt][nt][1] + bvn;
        float v2 = acc[mt][nt][2] + bvn, v3 = acc[mt][nt][3] + bvn;
        uint2 pk;
        asm("v_cvt_pk_bf16_f32 %0, %1, %2" : "=v"(pk.x) : "v"(v0), "v"(v1));
        asm("v_cvt_pk_bf16_f32 %0, %1, %2" : "=v"(pk.y) : "v"(v2), "v"(v3));
        *(uint2*)(Ts + col * 136 + wm + 16 * mt + 4 * g) = pk;
      }
    }
    __syncthreads();
    int vcol = t >> 1, half = t & 1;
    int gc = n0 - 1024 + vcol;
    int bh = (m0 >> 11) * 8 + (gc >> 6);
    int d  = gc & 63;
    unsigned short* dst = VT + ((size_t)bh * 64 + d) * 2048 + (m0 & 2047) + half * 64;
    const unsigned short* srcp = Ts + vcol * 136 + half * 64;
#pragma unroll
    for (int j2 = 0; j2 < 8; j2++)
      *(bf16x8*)(dst + j2 * 8) = *(const bf16x8*)(srcp + j2 * 8);
    return;
  }

#pragma unroll
  for (int mt = 0; mt < 4; mt++) {
#pragma unroll
    for (int i = 0; i < 4; i++) {
      size_t roff = (size_t)(m0 + wm + 16 * mt + 4 * g + i) * N;
#pragma unroll
      for (int nt = 0; nt < NFR; nt++) {
        int col = n0 + wn + 16 * nt + li;
        float v = acc[mt][nt][i] + bv[nt];
        if (EPI == 1) {
          v += R[roff + col];
          Yf[roff + col] = v;
        } else if (EPI == 2) {
          v = v / (1.f + __expf(-v));
          Yb[roff + col] = f2bf(v);
        } else if (EPI == 3) {
          Yf[roff + col] = v;
        } else {
          if (QSCALE && col < 512) v *= 0.18033688011112042f;  // 0.125*log2(e)
          Yb[roff + col] = f2bf(v);
        }
      }
    }
  }
}

// ---------------- MFMA flash attention, 2-phase pipelined, KVBLK=128 ----------
// QBLK=128; grid 512: bh = bid&31 (XCD-local), qi = bid>>5; 4 waves; Q prescaled.
// (round-9 version: VGPR 128, 2 blocks/CU — do not add registers here)
__global__ __launch_bounds__(256) void attn_mfma(
    const unsigned short* __restrict__ qkv,  // [8192,1536] bf16
    const unsigned short* __restrict__ Vt,   // [32,64,2048] bf16
    unsigned short* __restrict__ ctx)        // [8192,512] bf16
{
  const int L = 2048;
  int bh = blockIdx.x & 31, qi = blockIdx.x >> 5;   // same-bh blocks -> same XCD
  int b = bh >> 3, h = bh & 7;
  int q0 = qi << 7;
  size_t tb = (size_t)b * L;
  int t = threadIdx.x, lane = t & 63, wv = t >> 6;
  int g = lane >> 4, li = lane & 15;
  int lisw = li & 7;

  // smem: buf{0,1}: [K 16K | V 16K] at 0/32768 ; P 16K at 65536 (4K/wave)
  __shared__ __align__(16) char smem[81920];

  int wq = q0 + wv * 32;
  bf16x8 qf00, qf01, qf10, qf11;
  {
    const unsigned short* qp0 = qkv + (tb + wq + li) * 1536 + h * 64 + g * 8;
    qf00 = *(const bf16x8*)qp0;
    qf01 = *(const bf16x8*)(qp0 + 32);
    const unsigned short* qp1 = qp0 + (size_t)16 * 1536;
    qf10 = *(const bf16x8*)qp1;
    qf11 = *(const bf16x8*)(qp1 + 32);
  }

  f32x4 accA[4], accB[4];
#pragma unroll
  for (int nt = 0; nt < 4; nt++) {
    accA[nt] = (f32x4){0.f, 0.f, 0.f, 0.f};
    accB[nt] = (f32x4){0.f, 0.f, 0.f, 0.f};
  }
  float mA = -1e30f, mB = -1e30f, lA = 0.f, lB = 0.f;

  // K fragment offsets (K region rows = 128B): row = 16mt+li
  int koff0 = li * 128 + ((g    ) ^ lisw) * 16;
  int koff1 = li * 128 + ((g + 4) ^ lisw) * 16;
  // V fragment offsets (V region rows = 256B, 16 slots): row = 16nt+li
  int vrowb = 16384 + li * 256;
  int vs00 = ((g    ) ^ lisw) << 4;     // pass 0, d-half 0
  int vs01 = ((g + 4) ^ lisw) << 4;     // pass 0, d-half 1
  int vs10 = ((8 + g) ^ lisw) << 4;     // pass 1, d-half 0
  int vs11 = ((12 + g) ^ lisw) << 4;    // pass 1, d-half 1
  // P pointers (wave-private 4KB at 65536)
  const char* pb0 = smem + 65536 + wv * 4096 + li * 128 + ((g    ) ^ lisw) * 16;
  const char* pb1 = smem + 65536 + wv * 4096 + li * 128 + ((g + 4) ^ lisw) * 16;
  char* pwbase = smem + 65536 + wv * 4096 + li * 128 + ((g & 1) << 3);
  char* pw0 = pwbase + (((0 + (g >> 1)) ^ lisw) << 4);
  char* pw1 = pwbase + (((2 + (g >> 1)) ^ lisw) << 4);
  char* pw2 = pwbase + (((4 + (g >> 1)) ^ lisw) << 4);
  char* pw3 = pwbase + (((6 + (g >> 1)) ^ lisw) << 4);

  // staging pointers: K 4 issues (rows 0..127), V 4 issues (rows 0..63)
  int subrow = lane >> 3;
  int coloff = ((lane & 7) ^ subrow) << 3;
  const unsigned short* kp[4];
  const unsigned short* vp[4];
#pragma unroll
  for (int j = 0; j < 4; j++) {
    int krow = (wv * 4 + j) * 8 + subrow;
    kp[j] = qkv + (tb + krow) * 1536 + 512 + h * 64 + coloff;
    int vrow = (wv * 4 + j) * 4 + g;
    vp[j] = Vt + ((size_t)bh * 64 + vrow) * 2048 + ((li ^ (vrow & 7)) << 3);
  }

  // prologue: stage tile 0 into buf 0
#pragma unroll
  for (int j = 0; j < 4; j++) {
    gload16(kp[j], (unsigned short*)(smem + (wv * 4 + j) * 1024));
    gload16(vp[j], (unsigned short*)(smem + 16384 + (wv * 4 + j) * 1024));
    kp[j] += (size_t)128 * 1536; vp[j] += 128;
  }
  pipe_sync();

#pragma unroll 2
  for (int it = 0; it < 16; it++) {
    const int buf = it & 1;
    const char* base = smem + buf * 32768;
    if (it < 15) {                    // issue next tile first (latency hides)
      char* nb = smem + (buf ^ 1) * 32768;
#pragma unroll
      for (int j = 0; j < 4; j++) {
        gload16(kp[j], (unsigned short*)(nb + (wv * 4 + j) * 1024));
        gload16(vp[j], (unsigned short*)(nb + 16384 + (wv * 4 + j) * 1024));
        kp[j] += (size_t)128 * 1536; vp[j] += 128;
      }
    }

    // S^T = K . Q^T over 128 keys (8 fragments per d-half)
    f32x4 sA[8], sB[8];
#pragma unroll
    for (int mt = 0; mt < 8; mt++) {
      sA[mt] = (f32x4){0.f, 0.f, 0.f, 0.f};
      sB[mt] = (f32x4){0.f, 0.f, 0.f, 0.f};
    }
    __builtin_amdgcn_s_setprio(1);
#pragma unroll
    for (int mt = 0; mt < 8; mt++) {
      bf16x8 kf = *(const bf16x8*)(base + koff0 + mt * 2048);
      sA[mt] = __builtin_amdgcn_mfma_f32_16x16x32_bf16(kf, qf00, sA[mt], 0, 0, 0);
      sB[mt] = __builtin_amdgcn_mfma_f32_16x16x32_bf16(kf, qf10, sB[mt], 0, 0, 0);
    }
#pragma unroll
    for (int mt = 0; mt < 8; mt++) {
      bf16x8 kf = *(const bf16x8*)(base + koff1 + mt * 2048);
      sA[mt] = __builtin_amdgcn_mfma_f32_16x16x32_bf16(kf, qf01, sA[mt], 0, 0, 0);
      sB[mt] = __builtin_amdgcn_mfma_f32_16x16x32_bf16(kf, qf11, sB[mt], 0, 0, 0);
    }
    __builtin_amdgcn_s_setprio(0);

    // tile maxes over 128 keys
    float mxA = -1e30f, mxB = -1e30f;
#pragma unroll
    for (int mt = 0; mt < 8; mt++) {
      mxA = fmaxf(mxA, fmaxf(fmaxf(sA[mt][0], sA[mt][1]), fmaxf(sA[mt][2], sA[mt][3])));
      mxB = fmaxf(mxB, fmaxf(fmaxf(sB[mt][0], sB[mt][1]), fmaxf(sB[mt][2], sB[mt][3])));
    }
    mxA = fmaxf(mxA, swz16f(mxA)); mxA = fmaxf(mxA, __shfl_xor(mxA, 32));
    mxB = fmaxf(mxB, swz16f(mxB)); mxB = fmaxf(mxB, __shfl_xor(mxB, 32));

    // defer-max (THR=8, exp2 domain)
    if (__any((mxA > mA + 8.0f) || (mxB > mB + 8.0f))) {
      float mnA = fmaxf(mA, mxA), mnB = fmaxf(mB, mxB);
      float cA = mA - mnA, cB = mB - mnB;
      asm volatile("v_exp_f32 %0, %0\n\tv_exp_f32 %1, %1\n\ts_nop 1"
                   : "+v"(cA), "+v"(cB));
      float c0 = __shfl(cA, 4 * g + 0), c1 = __shfl(cA, 4 * g + 1);
      float c2 = __shfl(cA, 4 * g + 2), c3 = __shfl(cA, 4 * g + 3);
#pragma unroll
      for (int nt = 0; nt < 4; nt++) {
        accA[nt][0] *= c0; accA[nt][1] *= c1;
        accA[nt][2] *= c2; accA[nt][3] *= c3;
      }
      float d0 = __shfl(cB, 4 * g + 0), d1 = __shfl(cB, 4 * g + 1);
      float d2 = __shfl(cB, 4 * g + 2), d3 = __shfl(cB, 4 * g + 3);
#pragma unroll
      for (int nt = 0; nt < 4; nt++) {
        accB[nt][0] *= d0; accB[nt][1] *= d1;
        accB[nt][2] *= d2; accB[nt][3] *= d3;
      }
      lA *= cA; lB *= cB;
      mA = mnA; mB = mnB;
    }

    float psA = 0.f, psB = 0.f;
#define PBLK(SARR, MM, PS, PWP, OFF)                                          \
    {                                                                         \
      float p0 = SARR[0] - MM, p1 = SARR[1] - MM,                             \
            p2 = SARR[2] - MM, p3 = SARR[3] - MM;                             \
      asm volatile("v_exp_f32 %0, %0\n\tv_exp_f32 %1, %1\n\t"                 \
                   "v_exp_f32 %2, %2\n\tv_exp_f32 %3, %3\n\ts_nop 1"          \
                   : "+v"(p0), "+v"(p1), "+v"(p2), "+v"(p3));                 \
      PS += (p0 + p1) + (p2 + p3);                                            \
      uint2 pv;                                                               \
      asm("v_cvt_pk_bf16_f32 %0, %1, %2" : "=v"(pv.x) : "v"(p0), "v"(p1));    \
      asm("v_cvt_pk_bf16_f32 %0, %1, %2" : "=v"(pv.y) : "v"(p2), "v"(p3));    \
      *(uint2*)(PWP + OFF) = pv;                                              \
    }
    // ---- pass 0: keys 0..63 ----
    PBLK(sA[0], mA, psA, pw0, 0) PBLK(sA[1], mA, psA, pw1, 0)
    PBLK(sA[2], mA, psA, pw2, 0) PBLK(sA[3], mA, psA, pw3, 0)
    PBLK(sB[0], mB, psB, pw0, 2048) PBLK(sB[1], mB, psB, pw1, 2048)
    PBLK(sB[2], mB, psB, pw2, 2048) PBLK(sB[3], mB, psB, pw3, 2048)
    {
      bf16x8 paA0 = *(const bf16x8*)(pb0);
      bf16x8 paB0 = *(const bf16x8*)(pb0 + 2048);
      __builtin_amdgcn_s_setprio(1);
#pragma unroll
      for (int nt = 0; nt < 4; nt++) {
        bf16x8 vb = *(const bf16x8*)(base + vrowb + nt * 4096 + vs00);
        accA[nt] = __builtin_amdgcn_mfma_f32_16x16x32_bf16(paA0, vb, accA[nt], 0, 0, 0);
        accB[nt] = __builtin_amdgcn_mfma_f32_16x16x32_bf16(paB0, vb, accB[nt], 0, 0, 0);
      }
      __builtin_amdgcn_s_setprio(0);
      bf16x8 paA1 = *(const bf16x8*)(pb1);
      bf16x8 paB1 = *(const bf16x8*)(pb1 + 2048);
      __builtin_amdgcn_s_setprio(1);
#pragma unroll
      for (int nt = 0; nt < 4; nt++) {
        bf16x8 vb = *(const bf16x8*)(base + vrowb + nt * 4096 + vs01);
        accA[nt] = __builtin_amdgcn_mfma_f32_16x16x32_bf16(paA1, vb, accA[nt], 0, 0, 0);
        accB[nt] = __builtin_amdgcn_mfma_f32_16x16x32_bf16(paB1, vb, accB[nt], 0, 0, 0);
      }
      __builtin_amdgcn_s_setprio(0);
    }
    // ---- pass 1: keys 64..127 (reuse wave-private P buffer) ----
    PBLK(sA[4], mA, psA, pw0, 0) PBLK(sA[5], mA, psA, pw1, 0)
    PBLK(sA[6], mA, psA, pw2, 0) PBLK(sA[7], mA, psA, pw3, 0)
    PBLK(sB[4], mB, psB, pw0, 2048) PBLK(sB[5], mB, psB, pw1, 2048)
    PBLK(sB[6], mB, psB, pw2, 2048) PBLK(sB[7], mB, psB, pw3, 2048)
#undef PBLK
    {
      bf16x8 paA0 = *(const bf16x8*)(pb0);
      bf16x8 paB0 = *(const bf16x8*)(pb0 + 2048);
      __builtin_amdgcn_s_setprio(1);
#pragma unroll
      for (int nt = 0; nt < 4; nt++) {
        bf16x8 vb = *(const bf16x8*)(base + vrowb + nt * 4096 + vs10);
        accA[nt] = __builtin_amdgcn_mfma_f32_16x16x32_bf16(paA0, vb, accA[nt], 0, 0, 0);
        accB[nt] = __builtin_amdgcn_mfma_f32_16x16x32_bf16(paB0, vb, accB[nt], 0, 0, 0);
      }
      __builtin_amdgcn_s_setprio(0);
      bf16x8 paA1 = *(const bf16x8*)(pb1);
      bf16x8 paB1 = *(const bf16x8*)(pb1 + 2048);
      __builtin_amdgcn_s_setprio(1);
#pragma unroll
      for (int nt = 0; nt < 4; nt++) {
        bf16x8 vb = *(const bf16x8*)(base + vrowb + nt * 4096 + vs11);
        accA[nt] = __builtin_amdgcn_mfma_f32_16x16x32_bf16(paA1, vb, accA[nt], 0, 0, 0);
        accB[nt] = __builtin_amdgcn_mfma_f32_16x16x32_bf16(paB1, vb, accB[nt], 0, 0, 0);
      }
      __builtin_amdgcn_s_setprio(0);
    }
    psA += swz16f(psA); psA += __shfl_xor(psA, 32); lA += psA;
    psB += swz16f(psB); psB += __shfl_xor(psB, 32); lB += psB;

    pipe_sync();
  }

  float liA[4], liB[4];
#pragma unroll
  for (int i = 0; i < 4; i++) {
    liA[i] = 1.f / __shfl(lA, 4 * g + i);
    liB[i] = 1.f / __shfl(lB, 4 * g + i);
  }
#pragma unroll
  for (int i = 0; i < 4; i++) {
    size_t ra = (tb + wq + 4 * g + i) * 512 + h * 64;
    size_t rb = (tb + wq + 16 + 4 * g + i) * 512 + h * 64;
#pragma unroll
    for (int nt = 0; nt < 4; nt++) {
      ctx[ra + 16 * nt + li] = f2bf(accA[nt][i] * liA[i]);
      ctx[rb + 16 * nt + li] = f2bf(accB[nt][i] * liB[i]);
    }
  }
}

// ---------------- LayerNorm over E=512; one wave per row; f32 + bf16 out ------
__global__ __launch_bounds__(256) void ln_kernel(
    const float* __restrict__ X, const float* __restrict__ g,
    const float* __restrict__ b, float* __restrict__ Yf,
    unsigned short* __restrict__ Yb)
{
  int t = threadIdx.x, lane = t & 63, wv = t >> 6;
  size_t row = (size_t)blockIdx.x * 4 + wv;
  const float* xp = X + row * 512 + lane * 8;
  float4 a = *(const float4*)xp;
  float4 c = *(const float4*)(xp + 4);
  float sum = a.x + a.y + a.z + a.w + c.x + c.y + c.z + c.w;
  float sq  = a.x*a.x + a.y*a.y + a.z*a.z + a.w*a.w
            + c.x*c.x + c.y*c.y + c.z*c.z + c.w*c.w;
#pragma unroll
  for (int off = 32; off > 0; off >>= 1) {
    sum += __shfl_xor(sum, off);
    sq  += __shfl_xor(sq, off);
  }
  float mu  = sum * (1.0f / 512.0f);
  float inv = rsqrtf(sq * (1.0f / 512.0f) - mu * mu + 1e-5f);
  float4 g0 = *(const float4*)(g + lane * 8);
  float4 g1 = *(const float4*)(g + lane * 8 + 4);
  float4 b0 = *(const float4*)(b + lane * 8);
  float4 b1 = *(const float4*)(b + lane * 8 + 4);
  float y[8];
  y[0] = (a.x - mu) * inv * g0.x + b0.x;
  y[1] = (a.y - mu) * inv * g0.y + b0.y;
  y[2] = (a.z - mu) * inv * g0.z + b0.z;
  y[3] = (a.w - mu) * inv * g0.w + b0.w;
  y[4] = (c.x - mu) * inv * g1.x + b1.x;
  y[5] = (c.y - mu) * inv * g1.y + b1.y;
  y[6] = (c.z - mu) * inv * g1.z + b1.z;
  y[7] = (c.w - mu) * inv * g1.w + b1.w;
  float4 y0 = {y[0], y[1], y[2], y[3]};
  float4 y1 = {y[4], y[5], y[6], y[7]};
  *(float4*)(Yf + row * 512 + lane * 8)     = y0;
  *(float4*)(Yf + row * 512 + lane * 8 + 4) = y1;
  bf16x8 yb;
#pragma unroll
  for (int j = 0; j < 8; j++) yb[j] = (short)f2bf(y[j]);
  *(bf16x8*)(Yb + row * 512 + lane * 8) = yb;
}

extern "C" void kernel_launch(void* const* d_in, const int* in_sizes, int n_in,
                              void* d_out, int out_size, void* d_ws, size_t ws_size,
                              hipStream_t stream) {
  (void)in_sizes; (void)n_in; (void)out_size; (void)ws_size;
  const float* x      = (const float*)d_in[0];
  const float* conv_w = (const float*)d_in[1];
  const float* conv_b = (const float*)d_in[2];
  const float* qkv_w  = (const float*)d_in[3];
  const float* qkv_b  = (const float*)d_in[4];
  const float* out_w  = (const float*)d_in[5];
  const float* out_b  = (const float*)d_in[6];
  const float* fc1_w  = (const float*)d_in[7];
  const float* fc1_b  = (const float*)d_in[8];
  const float* fc2_w  = (const float*)d_in[9];
  const float* fc2_b  = (const float*)d_in[10];
  const float* ln1_w  = (const float*)d_in[11];
  const float* ln1_b  = (const float*)d_in[12];
  const float* ln2_w  = (const float*)d_in[13];
  const float* ln2_b  = (const float*)d_in[14];
  const float* outp_w = (const float*)d_in[15];
  const float* outp_b = (const float*)d_in[16];
  float* out = (float*)d_out;

  char* p = (char*)d_ws;
  unsigned short* A_bf = (unsigned short*)p;            p += (size_t)8192 * 512 * 2;
  float*          A_f  = (float*)p;                     p += (size_t)8192 * 512 * 4;
  unsigned short* QKV  = (unsigned short*)p;            p += (size_t)8192 * 1536 * 2;
  unsigned short* VT   = (unsigned short*)p;            p += (size_t)32 * 64 * 2048 * 2;
  unsigned short* CTX  = (unsigned short*)p;            p += (size_t)8192 * 512 * 2;
  unsigned short* Wq   = (unsigned short*)p;            p += (size_t)4 * 1536 * 512 * 2;
  unsigned short* Wo   = (unsigned short*)p;            p += (size_t)4 * 512 * 512 * 2;
  unsigned short* W1   = (unsigned short*)p;            p += (size_t)4 * 512 * 512 * 2;
  unsigned short* W2   = (unsigned short*)p;            p += (size_t)4 * 512 * 512 * 2;
  unsigned short* Wp   = (unsigned short*)p;            p += (size_t)32 * 512 * 2;
  float* D = (float*)QKV;   // aliased: D[8192,512] f32 in QKV region (disjoint lifetime)

  cvt_all<<<6160, 256, 0, stream>>>(qkv_w, out_w, fc1_w, fc2_w, outp_w, Wq);

  conv_pe_kernel<<<1024, 256, 0, stream>>>(x, conv_w, conv_b, A_f, A_bf);

  for (int l = 0; l < 4; l++) {
    gemm_bf<0, 1, 4, 1><<<64 * 12, 256, 0, stream>>>(
        A_bf, Wq + (size_t)l * 1536 * 512, qkv_b + l * 1536, nullptr,
        QKV, nullptr, VT, 1536);
    attn_mfma<<<512, 256, 0, stream>>>(QKV, VT, CTX);
    gemm_bf<1, 0, 2, 0><<<64 * 8, 256, 0, stream>>>(
        CTX, Wo + (size_t)l * 512 * 512, out_b + l * 512, A_f,
        nullptr, D, nullptr, 512);
    ln_kernel<<<2048, 256, 0, stream>>>(D, ln1_w + l * 512, ln1_b + l * 512, A_f, A_bf);
    gemm_bf<2, 0, 2, 0><<<64 * 8, 256, 0, stream>>>(
        A_bf, W1 + (size_t)l * 512 * 512, fc1_b + l * 512, nullptr,
        CTX, nullptr, nullptr, 512);
    gemm_bf<1, 0, 2, 0><<<64 * 8, 256, 0, stream>>>(
        CTX, W2 + (size_t)l * 512 * 512, fc2_b + l * 512, A_f,
        nullptr, D, nullptr, 512);
    ln_kernel<<<2048, 256, 0, stream>>>(D, ln2_w + l * 512, ln2_b + l * 512, A_f, A_bf);
  }
  gemm_bf<3, 0, 1, 0><<<64, 256, 0, stream>>>(
      A_bf, Wp, outp_b, nullptr, nullptr, out, nullptr, 32);
}

// Round 12
// 499.113 us; speedup vs baseline: 1.2463x; 1.1377x over previous
//
#include <hip/hip_runtime.h>
#include <hip/hip_bf16.h>
#include <cstddef>

typedef short bf16x8 __attribute__((ext_vector_type(8)));
typedef float f32x4 __attribute__((ext_vector_type(4)));

__device__ __forceinline__ unsigned short f2bf(float x) {
  __hip_bfloat16 h = __float2bfloat16(x);
  unsigned short u; __builtin_memcpy(&u, &h, 2); return u;
}
__device__ __forceinline__ float bf2f(unsigned short u) {
  unsigned int v = ((unsigned int)u) << 16; float f; __builtin_memcpy(&f, &v, 4); return f;
}
__device__ __forceinline__ float swz16f(float x) {   // lane ^= 16 (within 32-group)
  int i; __builtin_memcpy(&i, &x, 4);
  i = __builtin_amdgcn_ds_swizzle(i, 0x401F);
  float r; __builtin_memcpy(&r, &i, 4); return r;
}
__device__ __forceinline__ void gload16(const unsigned short* g, unsigned short* l) {
  __builtin_amdgcn_global_load_lds(
      (const __attribute__((address_space(1))) void*)g,
      (__attribute__((address_space(3))) void*)l, 16, 0, 0);
}
__device__ __forceinline__ void pipe_sync() {
  asm volatile("s_waitcnt vmcnt(0)" ::: "memory");
  __builtin_amdgcn_s_barrier();
  __builtin_amdgcn_sched_barrier(0);
}

// ---------------- all weights fp32 -> bf16 (contiguous dst) ----------------
__global__ __launch_bounds__(256) void cvt_all(
    const float* __restrict__ qkv_w, const float* __restrict__ out_w,
    const float* __restrict__ fc1_w, const float* __restrict__ fc2_w,
    const float* __restrict__ outp_w, unsigned short* __restrict__ dst)
{
  int i = blockIdx.x * 256 + threadIdx.x;
  if (i >= 1576960) return;
  const float* src; int off;
  if (i < 786432)       { src = qkv_w;  off = i; }
  else if (i < 1048576) { src = out_w;  off = i - 786432; }
  else if (i < 1310720) { src = fc1_w;  off = i - 1048576; }
  else if (i < 1572864) { src = fc2_w;  off = i - 1310720; }
  else                  { src = outp_w; off = i - 1572864; }
  float4 v = *(const float4*)(src + (size_t)off * 4);
  ushort4 o;
  o.x = f2bf(v.x); o.y = f2bf(v.y); o.z = f2bf(v.z); o.w = f2bf(v.w);
  *(ushort4*)(dst + (size_t)i * 4) = o;
}

// ---------------- conv1d (circular, k=3) + positional embedding -> bf16 ------
__global__ __launch_bounds__(256) void conv_pe_kernel(
    const float* __restrict__ x, const float* __restrict__ cw,
    const float* __restrict__ cb, unsigned short* __restrict__ outb)
{
  const int L = 2048, CIN = 32;
  int b  = blockIdx.x >> 8;
  int l0 = (blockIdx.x & 255) << 3;
  int t  = threadIdx.x;
  __shared__ float xs[10][32];
  for (int idx = t; idx < 320; idx += 256) {
    int rr = idx >> 5, ci = idx & 31;
    int gl = (l0 - 1 + rr + L) & (L - 1);
    xs[rr][ci] = x[((size_t)b * L + gl) * CIN + ci];
  }
  __syncthreads();
  int e0 = t << 1;
  float acc0[8], acc1[8];
  float bb0 = cb[e0], bb1 = cb[e0 + 1];
#pragma unroll
  for (int li = 0; li < 8; li++) { acc0[li] = bb0; acc1[li] = bb1; }
  const float* w0p = cw + (size_t)e0 * 96;
  const float* w1p = w0p + 96;
  for (int ci = 0; ci < 32; ci++) {
#pragma unroll
    for (int kk = 0; kk < 3; kk++) {
      float w0 = w0p[ci * 3 + kk];
      float w1 = w1p[ci * 3 + kk];
#pragma unroll
      for (int li = 0; li < 8; li++) {
        float xv = xs[li + kk][ci];
        acc0[li] += xv * w0;
        acc1[li] += xv * w1;
      }
    }
  }
  float dv = __expf((float)e0 * (-9.210340371976184f / 512.0f));
#pragma unroll
  for (int li = 0; li < 8; li++) {
    int l = l0 + li;
    float arg = (float)l * dv;
    float sv = sinf(arg), cv = cosf(arg);
    size_t off = ((size_t)b * L + l) * 512 + e0;
    ushort2 ob; ob.x = f2bf(acc0[li] + sv); ob.y = f2bf(acc1[li] + cv);
    *(ushort2*)&outb[off] = ob;
  }
}

// ---------------- bf16 MFMA GEMM, 2-phase pipelined ----------------
// Y[M,N] = X[M,512] @ W[N,512]^T + bias.  Tile 128 x (NFR*32).
// EPI 0: Yb bf16 (QSCALE: cols<512 prescaled).  EPI 1: Yb bf16 = +R(bf16).
// EPI 2: SiLU->Yb.  EPI 3: Yf f32 (no residual).
// VOUT: n-blocks with n0>=1024 write TRANSPOSED into VT[32][64][2048] (V path).
template<int EPI, int QSCALE, int NFR, int VOUT>
__global__ __launch_bounds__(256) void gemm_bf(
    const unsigned short* __restrict__ X,
    const unsigned short* __restrict__ W,
    const float* __restrict__ bias,
    const unsigned short* __restrict__ R,
    unsigned short* __restrict__ Yb,
    float* __restrict__ Yf,
    unsigned short* __restrict__ VT,
    int N)
{
  const int K = 512;
  constexpr int BN = NFR * 32;
  constexpr int WB = NFR * 4096;          // W-region bytes per buffer
  constexpr int BUF = 16384 + WB;
  __shared__ __align__(16) char smem[2 * BUF];
  int t = threadIdx.x;
  int lane = t & 63, wv = t >> 6;
  int g = lane >> 4, li = lane & 15;
  int m0 = (blockIdx.x & 63) << 7;
  int n0 = (blockIdx.x >> 6) * BN;
  int wm = (wv >> 1) << 6;
  int wn = (wv & 1) * (BN / 2);

  int subrow = lane >> 3;
  int coloff = ((lane & 7) ^ subrow) << 3;   // inverse swizzle on global source

  f32x4 acc[4][NFR];
#pragma unroll
  for (int a = 0; a < 4; a++)
#pragma unroll
    for (int b2 = 0; b2 < NFR; b2++) acc[a][b2] = (f32x4){0.f, 0.f, 0.f, 0.f};

  // prologue: stage k-step 0 into buf 0
#pragma unroll
  for (int j = 0; j < 4; j++) {
    int row = (wv * 4 + j) * 8 + subrow;
    gload16(X + (size_t)(m0 + row) * K + coloff,
            (unsigned short*)(smem + (wv * 4 + j) * 1024));
  }
#pragma unroll
  for (int j = 0; j < NFR; j++) {
    int row = (wv * NFR + j) * 8 + subrow;
    gload16(W + (size_t)(n0 + row) * K + coloff,
            (unsigned short*)(smem + 16384 + (wv * NFR + j) * 1024));
  }
  pipe_sync();

#pragma unroll
  for (int ks = 0; ks < 8; ks++) {
    const int buf = ks & 1;
    char* cur = smem + buf * BUF;
    if (ks < 7) {                     // issue next-tile loads first
      char* nxt = smem + (buf ^ 1) * BUF;
      int k0 = (ks + 1) * 64;
#pragma unroll
      for (int j = 0; j < 4; j++) {
        int row = (wv * 4 + j) * 8 + subrow;
        gload16(X + (size_t)(m0 + row) * K + k0 + coloff,
                (unsigned short*)(nxt + (wv * 4 + j) * 1024));
      }
#pragma unroll
      for (int j = 0; j < NFR; j++) {
        int row = (wv * NFR + j) * 8 + subrow;
        gload16(W + (size_t)(n0 + row) * K + k0 + coloff,
                (unsigned short*)(nxt + 16384 + (wv * NFR + j) * 1024));
      }
    }
#pragma unroll
    for (int s = 0; s < 2; s++) {
      bf16x8 af[4], bfr[NFR];
#pragma unroll
      for (int mt = 0; mt < 4; mt++) {
        int row = wm + 16 * mt + li;
        af[mt] = *(const bf16x8*)(cur + (row * 8 + ((g + 4 * s) ^ (row & 7))) * 16);
      }
#pragma unroll
      for (int nt = 0; nt < NFR; nt++) {
        int row = wn + 16 * nt + li;
        bfr[nt] = *(const bf16x8*)(cur + 16384 +
                                   (row * 8 + ((g + 4 * s) ^ (row & 7))) * 16);
      }
#pragma unroll
      for (int mt = 0; mt < 4; mt++)
#pragma unroll
        for (int nt = 0; nt < NFR; nt++)
          acc[mt][nt] = __builtin_amdgcn_mfma_f32_16x16x32_bf16(
              af[mt], bfr[nt], acc[mt][nt], 0, 0, 0);
    }
    pipe_sync();
  }

  float bv[NFR];
#pragma unroll
  for (int nt = 0; nt < NFR; nt++) bv[nt] = bias[n0 + wn + 16 * nt + li];

  if (VOUT && n0 >= 1024) {
    // transposed V output: LDS bounce (rows = tile cols, stride 136 shorts)
    unsigned short* Ts = (unsigned short*)smem;
#pragma unroll
    for (int nt = 0; nt < NFR; nt++) {
      int col = wn + 16 * nt + li;
      float bvn = bv[nt];
#pragma unroll
      for (int mt = 0; mt < 4; mt++) {
        float v0 = acc[mt][nt][0] + bvn, v1 = acc[mt][nt][1] + bvn;
        float v2 = acc[mt][nt][2] + bvn, v3 = acc[mt][nt][3] + bvn;
        uint2 pk;
        asm("v_cvt_pk_bf16_f32 %0, %1, %2" : "=v"(pk.x) : "v"(v0), "v"(v1));
        asm("v_cvt_pk_bf16_f32 %0, %1, %2" : "=v"(pk.y) : "v"(v2), "v"(v3));
        *(uint2*)(Ts + col * 136 + wm + 16 * mt + 4 * g) = pk;
      }
    }
    __syncthreads();
    int vcol = t >> 1, half = t & 1;
    int gc = n0 - 1024 + vcol;
    int bh = (m0 >> 11) * 8 + (gc >> 6);
    int d  = gc & 63;
    unsigned short* dst = VT + ((size_t)bh * 64 + d) * 2048 + (m0 & 2047) + half * 64;
    const unsigned short* srcp = Ts + vcol * 136 + half * 64;
#pragma unroll
    for (int j2 = 0; j2 < 8; j2++)
      *(bf16x8*)(dst + j2 * 8) = *(const bf16x8*)(srcp + j2 * 8);
    return;
  }

#pragma unroll
  for (int mt = 0; mt < 4; mt++) {
#pragma unroll
    for (int i = 0; i < 4; i++) {
      size_t roff = (size_t)(m0 + wm + 16 * mt + 4 * g + i) * N;
#pragma unroll
      for (int nt = 0; nt < NFR; nt++) {
        int col = n0 + wn + 16 * nt + li;
        float v = acc[mt][nt][i] + bv[nt];
        if (EPI == 1) {
          v += bf2f(R[roff + col]);
          Yb[roff + col] = f2bf(v);
        } else if (EPI == 2) {
          v = v / (1.f + __expf(-v));
          Yb[roff + col] = f2bf(v);
        } else if (EPI == 3) {
          Yf[roff + col] = v;
        } else {
          if (QSCALE && col < 512) v *= 0.18033688011112042f;  // 0.125*log2(e)
          Yb[roff + col] = f2bf(v);
        }
      }
    }
  }
}

// ---------------- MFMA flash attention, 2-phase pipelined, KVBLK=128 ----------
// QBLK=128; grid 512: bh = bid&31 (XCD-local), qi = bid>>5; 4 waves.
// Q prescaled by 0.125*log2(e); softmax is NO-MAX: p = 2^s directly
// (scale-invariant; scores bounded |s| << 120 so 2^s never overflows f32).
__global__ __launch_bounds__(256) void attn_mfma(
    const unsigned short* __restrict__ qkv,  // [8192,1536] bf16
    const unsigned short* __restrict__ Vt,   // [32,64,2048] bf16
    unsigned short* __restrict__ ctx)        // [8192,512] bf16
{
  const int L = 2048;
  int bh = blockIdx.x & 31, qi = blockIdx.x >> 5;   // same-bh blocks -> same XCD
  int b = bh >> 3, h = bh & 7;
  int q0 = qi << 7;
  size_t tb = (size_t)b * L;
  int t = threadIdx.x, lane = t & 63, wv = t >> 6;
  int g = lane >> 4, li = lane & 15;
  int lisw = li & 7;

  // smem: buf{0,1}: [K 16K | V 16K] at 0/32768 ; P 16K at 65536 (4K/wave)
  __shared__ __align__(16) char smem[81920];

  int wq = q0 + wv * 32;
  bf16x8 qf00, qf01, qf10, qf11;
  {
    const unsigned short* qp0 = qkv + (tb + wq + li) * 1536 + h * 64 + g * 8;
    qf00 = *(const bf16x8*)qp0;
    qf01 = *(const bf16x8*)(qp0 + 32);
    const unsigned short* qp1 = qp0 + (size_t)16 * 1536;
    qf10 = *(const bf16x8*)qp1;
    qf11 = *(const bf16x8*)(qp1 + 32);
  }

  f32x4 accA[4], accB[4];
#pragma unroll
  for (int nt = 0; nt < 4; nt++) {
    accA[nt] = (f32x4){0.f, 0.f, 0.f, 0.f};
    accB[nt] = (f32x4){0.f, 0.f, 0.f, 0.f};
  }
  float lA = 0.f, lB = 0.f;

  // K fragment offsets (K region rows = 128B): row = 16mt+li
  int koff0 = li * 128 + ((g    ) ^ lisw) * 16;
  int koff1 = li * 128 + ((g + 4) ^ lisw) * 16;
  // V fragment offsets (V region rows = 256B, 16 slots): row = 16nt+li
  int vrowb = 16384 + li * 256;
  int vs00 = ((g    ) ^ lisw) << 4;     // pass 0, d-half 0
  int vs01 = ((g + 4) ^ lisw) << 4;     // pass 0, d-half 1
  int vs10 = ((8 + g) ^ lisw) << 4;     // pass 1, d-half 0
  int vs11 = ((12 + g) ^ lisw) << 4;    // pass 1, d-half 1
  // P pointers (wave-private 4KB at 65536)
  const char* pb0 = smem + 65536 + wv * 4096 + li * 128 + ((g    ) ^ lisw) * 16;
  const char* pb1 = smem + 65536 + wv * 4096 + li * 128 + ((g + 4) ^ lisw) * 16;
  char* pwbase = smem + 65536 + wv * 4096 + li * 128 + ((g & 1) << 3);
  char* pw0 = pwbase + (((0 + (g >> 1)) ^ lisw) << 4);
  char* pw1 = pwbase + (((2 + (g >> 1)) ^ lisw) << 4);
  char* pw2 = pwbase + (((4 + (g >> 1)) ^ lisw) << 4);
  char* pw3 = pwbase + (((6 + (g >> 1)) ^ lisw) << 4);

  // staging pointers: K 4 issues (rows 0..127), V 4 issues (rows 0..63)
  int subrow = lane >> 3;
  int coloff = ((lane & 7) ^ subrow) << 3;
  const unsigned short* kp[4];
  const unsigned short* vp[4];
#pragma unroll
  for (int j = 0; j < 4; j++) {
    int krow = (wv * 4 + j) * 8 + subrow;
    kp[j] = qkv + (tb + krow) * 1536 + 512 + h * 64 + coloff;
    int vrow = (wv * 4 + j) * 4 + g;
    vp[j] = Vt + ((size_t)bh * 64 + vrow) * 2048 + ((li ^ (vrow & 7)) << 3);
  }

  // prologue: stage tile 0 into buf 0
#pragma unroll
  for (int j = 0; j < 4; j++) {
    gload16(kp[j], (unsigned short*)(smem + (wv * 4 + j) * 1024));
    gload16(vp[j], (unsigned short*)(smem + 16384 + (wv * 4 + j) * 1024));
    kp[j] += (size_t)128 * 1536; vp[j] += 128;
  }
  pipe_sync();

#pragma unroll 2
  for (int it = 0; it < 16; it++) {
    const int buf = it & 1;
    const char* base = smem + buf * 32768;
    if (it < 15) {                    // issue next tile first (latency hides)
      char* nb = smem + (buf ^ 1) * 32768;
#pragma unroll
      for (int j = 0; j < 4; j++) {
        gload16(kp[j], (unsigned short*)(nb + (wv * 4 + j) * 1024));
        gload16(vp[j], (unsigned short*)(nb + 16384 + (wv * 4 + j) * 1024));
        kp[j] += (size_t)128 * 1536; vp[j] += 128;
      }
    }

    // S^T = K . Q^T over 128 keys (8 fragments per d-half)
    f32x4 sA[8], sB[8];
#pragma unroll
    for (int mt = 0; mt < 8; mt++) {
      sA[mt] = (f32x4){0.f, 0.f, 0.f, 0.f};
      sB[mt] = (f32x4){0.f, 0.f, 0.f, 0.f};
    }
    __builtin_amdgcn_s_setprio(1);
#pragma unroll
    for (int mt = 0; mt < 8; mt++) {
      bf16x8 kf = *(const bf16x8*)(base + koff0 + mt * 2048);
      sA[mt] = __builtin_amdgcn_mfma_f32_16x16x32_bf16(kf, qf00, sA[mt], 0, 0, 0);
      sB[mt] = __builtin_amdgcn_mfma_f32_16x16x32_bf16(kf, qf10, sB[mt], 0, 0, 0);
    }
#pragma unroll
    for (int mt = 0; mt < 8; mt++) {
      bf16x8 kf = *(const bf16x8*)(base + koff1 + mt * 2048);
      sA[mt] = __builtin_amdgcn_mfma_f32_16x16x32_bf16(kf, qf01, sA[mt], 0, 0, 0);
      sB[mt] = __builtin_amdgcn_mfma_f32_16x16x32_bf16(kf, qf11, sB[mt], 0, 0, 0);
    }
    __builtin_amdgcn_s_setprio(0);

    // NO-MAX softmax: p = 2^s directly; accumulate row-sum l
    float psA = 0.f, psB = 0.f;
#define PBLK(SARR, PS, PWP, OFF)                                              \
    {                                                                         \
      float p0 = SARR[0], p1 = SARR[1], p2 = SARR[2], p3 = SARR[3];           \
      asm volatile("v_exp_f32 %0, %0\n\tv_exp_f32 %1, %1\n\t"                 \
                   "v_exp_f32 %2, %2\n\tv_exp_f32 %3, %3\n\ts_nop 1"          \
                   : "+v"(p0), "+v"(p1), "+v"(p2), "+v"(p3));                 \
      PS += (p0 + p1) + (p2 + p3);                                            \
      uint2 pv;                                                               \
      asm("v_cvt_pk_bf16_f32 %0, %1, %2" : "=v"(pv.x) : "v"(p0), "v"(p1));    \
      asm("v_cvt_pk_bf16_f32 %0, %1, %2" : "=v"(pv.y) : "v"(p2), "v"(p3));    \
      *(uint2*)(PWP + OFF) = pv;                                              \
    }
    // ---- pass 0: keys 0..63 ----
    PBLK(sA[0], psA, pw0, 0) PBLK(sA[1], psA, pw1, 0)
    PBLK(sA[2], psA, pw2, 0) PBLK(sA[3], psA, pw3, 0)
    PBLK(sB[0], psB, pw0, 2048) PBLK(sB[1], psB, pw1, 2048)
    PBLK(sB[2], psB, pw2, 2048) PBLK(sB[3], psB, pw3, 2048)
    {
      bf16x8 paA0 = *(const bf16x8*)(pb0);
      bf16x8 paB0 = *(const bf16x8*)(pb0 + 2048);
      __builtin_amdgcn_s_setprio(1);
#pragma unroll
      for (int nt = 0; nt < 4; nt++) {
        bf16x8 vb = *(const bf16x8*)(base + vrowb + nt * 4096 + vs00);
        accA[nt] = __builtin_amdgcn_mfma_f32_16x16x32_bf16(paA0, vb, accA[nt], 0, 0, 0);
        accB[nt] = __builtin_amdgcn_mfma_f32_16x16x32_bf16(paB0, vb, accB[nt], 0, 0, 0);
      }
      __builtin_amdgcn_s_setprio(0);
      bf16x8 paA1 = *(const bf16x8*)(pb1);
      bf16x8 paB1 = *(const bf16x8*)(pb1 + 2048);
      __builtin_amdgcn_s_setprio(1);
#pragma unroll
      for (int nt = 0; nt < 4; nt++) {
        bf16x8 vb = *(const bf16x8*)(base + vrowb + nt * 4096 + vs01);
        accA[nt] = __builtin_amdgcn_mfma_f32_16x16x32_bf16(paA1, vb, accA[nt], 0, 0, 0);
        accB[nt] = __builtin_amdgcn_mfma_f32_16x16x32_bf16(paB1, vb, accB[nt], 0, 0, 0);
      }
      __builtin_amdgcn_s_setprio(0);
    }
    // ---- pass 1: keys 64..127 (reuse wave-private P buffer) ----
    PBLK(sA[4], psA, pw0, 0) PBLK(sA[5], psA, pw1, 0)
    PBLK(sA[6], psA, pw2, 0) PBLK(sA[7], psA, pw3, 0)
    PBLK(sB[4], psB, pw0, 2048) PBLK(sB[5], psB, pw1, 2048)
    PBLK(sB[6], psB, pw2, 2048) PBLK(sB[7], psB, pw3, 2048)
#undef PBLK
    {
      bf16x8 paA0 = *(const bf16x8*)(pb0);
      bf16x8 paB0 = *(const bf16x8*)(pb0 + 2048);
      __builtin_amdgcn_s_setprio(1);
#pragma unroll
      for (int nt = 0; nt < 4; nt++) {
        bf16x8 vb = *(const bf16x8*)(base + vrowb + nt * 4096 + vs10);
        accA[nt] = __builtin_amdgcn_mfma_f32_16x16x32_bf16(paA0, vb, accA[nt], 0, 0, 0);
        accB[nt] = __builtin_amdgcn_mfma_f32_16x16x32_bf16(paB0, vb, accB[nt], 0, 0, 0);
      }
      __builtin_amdgcn_s_setprio(0);
      bf16x8 paA1 = *(const bf16x8*)(pb1);
      bf16x8 paB1 = *(const bf16x8*)(pb1 + 2048);
      __builtin_amdgcn_s_setprio(1);
#pragma unroll
      for (int nt = 0; nt < 4; nt++) {
        bf16x8 vb = *(const bf16x8*)(base + vrowb + nt * 4096 + vs11);
        accA[nt] = __builtin_amdgcn_mfma_f32_16x16x32_bf16(paA1, vb, accA[nt], 0, 0, 0);
        accB[nt] = __builtin_amdgcn_mfma_f32_16x16x32_bf16(paB1, vb, accB[nt], 0, 0, 0);
      }
      __builtin_amdgcn_s_setprio(0);
    }
    psA += swz16f(psA); psA += __shfl_xor(psA, 32); lA += psA;
    psB += swz16f(psB); psB += __shfl_xor(psB, 32); lB += psB;

    pipe_sync();
  }

  float liA[4], liB[4];
#pragma unroll
  for (int i = 0; i < 4; i++) {
    liA[i] = 1.f / __shfl(lA, 4 * g + i);
    liB[i] = 1.f / __shfl(lB, 4 * g + i);
  }
#pragma unroll
  for (int i = 0; i < 4; i++) {
    size_t ra = (tb + wq + 4 * g + i) * 512 + h * 64;
    size_t rb = (tb + wq + 16 + 4 * g + i) * 512 + h * 64;
#pragma unroll
    for (int nt = 0; nt < 4; nt++) {
      ctx[ra + 16 * nt + li] = f2bf(accA[nt][i] * liA[i]);
      ctx[rb + 16 * nt + li] = f2bf(accB[nt][i] * liB[i]);
    }
  }
}

// ---------------- LayerNorm over E=512 (bf16 in, bf16 out); one wave/row -----
__global__ __launch_bounds__(256) void ln_kernel(
    const unsigned short* __restrict__ X, const float* __restrict__ g,
    const float* __restrict__ b, unsigned short* __restrict__ Yb)
{
  int t = threadIdx.x, lane = t & 63, wv = t >> 6;
  size_t row = (size_t)blockIdx.x * 4 + wv;
  bf16x8 xv = *(const bf16x8*)(X + row * 512 + lane * 8);
  float xf[8];
#pragma unroll
  for (int j = 0; j < 8; j++) xf[j] = bf2f((unsigned short)xv[j]);
  float sum = 0.f, sq = 0.f;
#pragma unroll
  for (int j = 0; j < 8; j++) { sum += xf[j]; sq += xf[j] * xf[j]; }
#pragma unroll
  for (int off = 32; off > 0; off >>= 1) {
    sum += __shfl_xor(sum, off);
    sq  += __shfl_xor(sq, off);
  }
  float mu  = sum * (1.0f / 512.0f);
  float inv = rsqrtf(sq * (1.0f / 512.0f) - mu * mu + 1e-5f);
  float4 g0 = *(const float4*)(g + lane * 8);
  float4 g1 = *(const float4*)(g + lane * 8 + 4);
  float4 b0 = *(const float4*)(b + lane * 8);
  float4 b1 = *(const float4*)(b + lane * 8 + 4);
  float gw[8] = {g0.x, g0.y, g0.z, g0.w, g1.x, g1.y, g1.z, g1.w};
  float bw[8] = {b0.x, b0.y, b0.z, b0.w, b1.x, b1.y, b1.z, b1.w};
  bf16x8 yb;
#pragma unroll
  for (int j = 0; j < 8; j++)
    yb[j] = (short)f2bf((xf[j] - mu) * inv * gw[j] + bw[j]);
  *(bf16x8*)(Yb + row * 512 + lane * 8) = yb;
}

extern "C" void kernel_launch(void* const* d_in, const int* in_sizes, int n_in,
                              void* d_out, int out_size, void* d_ws, size_t ws_size,
                              hipStream_t stream) {
  (void)in_sizes; (void)n_in; (void)out_size; (void)ws_size;
  const float* x      = (const float*)d_in[0];
  const float* conv_w = (const float*)d_in[1];
  const float* conv_b = (const float*)d_in[2];
  const float* qkv_w  = (const float*)d_in[3];
  const float* qkv_b  = (const float*)d_in[4];
  const float* out_w  = (const float*)d_in[5];
  const float* out_b  = (const float*)d_in[6];
  const float* fc1_w  = (const float*)d_in[7];
  const float* fc1_b  = (const float*)d_in[8];
  const float* fc2_w  = (const float*)d_in[9];
  const float* fc2_b  = (const float*)d_in[10];
  const float* ln1_w  = (const float*)d_in[11];
  const float* ln1_b  = (const float*)d_in[12];
  const float* ln2_w  = (const float*)d_in[13];
  const float* ln2_b  = (const float*)d_in[14];
  const float* outp_w = (const float*)d_in[15];
  const float* outp_b = (const float*)d_in[16];
  float* out = (float*)d_out;

  char* p = (char*)d_ws;
  unsigned short* A    = (unsigned short*)p;            p += (size_t)8192 * 512 * 2;
  unsigned short* QKV  = (unsigned short*)p;            p += (size_t)8192 * 1536 * 2;
  unsigned short* VT   = (unsigned short*)p;            p += (size_t)32 * 64 * 2048 * 2;
  unsigned short* CTX  = (unsigned short*)p;            p += (size_t)8192 * 512 * 2;
  unsigned short* Wq   = (unsigned short*)p;            p += (size_t)4 * 1536 * 512 * 2;
  unsigned short* Wo   = (unsigned short*)p;            p += (size_t)4 * 512 * 512 * 2;
  unsigned short* W1   = (unsigned short*)p;            p += (size_t)4 * 512 * 512 * 2;
  unsigned short* W2   = (unsigned short*)p;            p += (size_t)4 * 512 * 512 * 2;
  unsigned short* Wp   = (unsigned short*)p;            p += (size_t)32 * 512 * 2;
  unsigned short* D = QKV;   // aliased: D[8192,512] bf16 in QKV region (disjoint lifetime)

  cvt_all<<<6160, 256, 0, stream>>>(qkv_w, out_w, fc1_w, fc2_w, outp_w, Wq);

  conv_pe_kernel<<<1024, 256, 0, stream>>>(x, conv_w, conv_b, A);

  for (int l = 0; l < 4; l++) {
    gemm_bf<0, 1, 4, 1><<<64 * 12, 256, 0, stream>>>(
        A, Wq + (size_t)l * 1536 * 512, qkv_b + l * 1536, nullptr,
        QKV, nullptr, VT, 1536);
    attn_mfma<<<512, 256, 0, stream>>>(QKV, VT, CTX);
    gemm_bf<1, 0, 2, 0><<<64 * 8, 256, 0, stream>>>(
        CTX, Wo + (size_t)l * 512 * 512, out_b + l * 512, A,
        D, nullptr, nullptr, 512);
    ln_kernel<<<2048, 256, 0, stream>>>(D, ln1_w + l * 512, ln1_b + l * 512, A);
    gemm_bf<2, 0, 2, 0><<<64 * 8, 256, 0, stream>>>(
        A, W1 + (size_t)l * 512 * 512, fc1_b + l * 512, nullptr,
        CTX, nullptr, nullptr, 512);
    gemm_bf<1, 0, 2, 0><<<64 * 8, 256, 0, stream>>>(
        CTX, W2 + (size_t)l * 512 * 512, fc2_b + l * 512, A,
        D, nullptr, nullptr, 512);
    ln_kernel<<<2048, 256, 0, stream>>>(D, ln2_w + l * 512, ln2_b + l * 512, A);
  }
  gemm_bf<3, 0, 1, 0><<<64, 256, 0, stream>>>(
      A, Wp, outp_b, nullptr, nullptr, out, nullptr, 32);
}

// Round 13
// 481.400 us; speedup vs baseline: 1.2922x; 1.0368x over previous
//
#include <hip/hip_runtime.h>
#include <hip/hip_bf16.h>
#include <cstddef>

typedef short bf16x8 __attribute__((ext_vector_type(8)));
typedef float f32x4 __attribute__((ext_vector_type(4)));

__device__ __forceinline__ unsigned short f2bf(float x) {
  __hip_bfloat16 h = __float2bfloat16(x);
  unsigned short u; __builtin_memcpy(&u, &h, 2); return u;
}
__device__ __forceinline__ float bf2f(unsigned short u) {
  unsigned int v = ((unsigned int)u) << 16; float f; __builtin_memcpy(&f, &v, 4); return f;
}
__device__ __forceinline__ float swz16f(float x) {   // lane ^= 16 (within 32-group)
  int i; __builtin_memcpy(&i, &x, 4);
  i = __builtin_amdgcn_ds_swizzle(i, 0x401F);
  float r; __builtin_memcpy(&r, &i, 4); return r;
}
__device__ __forceinline__ void gload16(const unsigned short* g, unsigned short* l) {
  __builtin_amdgcn_global_load_lds(
      (const __attribute__((address_space(1))) void*)g,
      (__attribute__((address_space(3))) void*)l, 16, 0, 0);
}
__device__ __forceinline__ void pipe_sync() {
  asm volatile("s_waitcnt vmcnt(0)" ::: "memory");
  __builtin_amdgcn_s_barrier();
  __builtin_amdgcn_sched_barrier(0);
}
__device__ __forceinline__ void bar_only() {
  asm volatile("" ::: "memory");
  __builtin_amdgcn_s_barrier();
  __builtin_amdgcn_sched_barrier(0);
}

// ---------------- all weights fp32 -> bf16 (contiguous dst) ----------------
__global__ __launch_bounds__(256) void cvt_all(
    const float* __restrict__ qkv_w, const float* __restrict__ out_w,
    const float* __restrict__ fc1_w, const float* __restrict__ fc2_w,
    const float* __restrict__ outp_w, unsigned short* __restrict__ dst)
{
  int i = blockIdx.x * 256 + threadIdx.x;
  if (i >= 1576960) return;
  const float* src; int off;
  if (i < 786432)       { src = qkv_w;  off = i; }
  else if (i < 1048576) { src = out_w;  off = i - 786432; }
  else if (i < 1310720) { src = fc1_w;  off = i - 1048576; }
  else if (i < 1572864) { src = fc2_w;  off = i - 1310720; }
  else                  { src = outp_w; off = i - 1572864; }
  float4 v = *(const float4*)(src + (size_t)off * 4);
  ushort4 o;
  o.x = f2bf(v.x); o.y = f2bf(v.y); o.z = f2bf(v.z); o.w = f2bf(v.w);
  *(ushort4*)(dst + (size_t)i * 4) = o;
}

// ---------------- conv1d (circular, k=3) + positional embedding -> bf16 ------
__global__ __launch_bounds__(256) void conv_pe_kernel(
    const float* __restrict__ x, const float* __restrict__ cw,
    const float* __restrict__ cb, unsigned short* __restrict__ outb)
{
  const int L = 2048, CIN = 32;
  int b  = blockIdx.x >> 8;
  int l0 = (blockIdx.x & 255) << 3;
  int t  = threadIdx.x;
  __shared__ float xs[10][32];
  for (int idx = t; idx < 320; idx += 256) {
    int rr = idx >> 5, ci = idx & 31;
    int gl = (l0 - 1 + rr + L) & (L - 1);
    xs[rr][ci] = x[((size_t)b * L + gl) * CIN + ci];
  }
  __syncthreads();
  int e0 = t << 1;
  float acc0[8], acc1[8];
  float bb0 = cb[e0], bb1 = cb[e0 + 1];
#pragma unroll
  for (int li = 0; li < 8; li++) { acc0[li] = bb0; acc1[li] = bb1; }
  const float* w0p = cw + (size_t)e0 * 96;
  const float* w1p = w0p + 96;
  for (int ci = 0; ci < 32; ci++) {
#pragma unroll
    for (int kk = 0; kk < 3; kk++) {
      float w0 = w0p[ci * 3 + kk];
      float w1 = w1p[ci * 3 + kk];
#pragma unroll
      for (int li = 0; li < 8; li++) {
        float xv = xs[li + kk][ci];
        acc0[li] += xv * w0;
        acc1[li] += xv * w1;
      }
    }
  }
  float dv = __expf((float)e0 * (-9.210340371976184f / 512.0f));
#pragma unroll
  for (int li = 0; li < 8; li++) {
    int l = l0 + li;
    float arg = (float)l * dv;
    float sv = sinf(arg), cv = cosf(arg);
    size_t off = ((size_t)b * L + l) * 512 + e0;
    ushort2 ob; ob.x = f2bf(acc0[li] + sv); ob.y = f2bf(acc1[li] + cv);
    *(ushort2*)&outb[off] = ob;
  }
}

// ---------------- bf16 MFMA GEMM, 2-phase pipelined, counted vmcnt (T4) ------
// Y[M,N] = X[M,512] @ W[N,512]^T + bias.  Tile 128 x (NFR*32).
// EPI 0: Yb bf16 (QSCALE: cols<512 prescaled).  EPI 1: Yb bf16 = +R(bf16).
// EPI 2: SiLU->Yb.  EPI 3: Yf f32 (no residual).
// VOUT: n-blocks with n0>=1024 write TRANSPOSED into VT[32][64][2048] (V path).
template<int EPI, int QSCALE, int NFR, int VOUT>
__global__ __launch_bounds__(256) void gemm_bf(
    const unsigned short* __restrict__ X,
    const unsigned short* __restrict__ W,
    const float* __restrict__ bias,
    const unsigned short* __restrict__ R,
    unsigned short* __restrict__ Yb,
    float* __restrict__ Yf,
    unsigned short* __restrict__ VT,
    int N)
{
  const int K = 512;
  constexpr int BN = NFR * 32;
  constexpr int WB = NFR * 4096;          // W-region bytes per buffer
  constexpr int BUF = 16384 + WB;
  __shared__ __align__(16) char smem[2 * BUF];
  int t = threadIdx.x;
  int lane = t & 63, wv = t >> 6;
  int g = lane >> 4, li = lane & 15;
  int m0 = (blockIdx.x & 63) << 7;
  int n0 = (blockIdx.x >> 6) * BN;
  int wm = (wv >> 1) << 6;
  int wn = (wv & 1) * (BN / 2);

  int subrow = lane >> 3;
  int coloff = ((lane & 7) ^ subrow) << 3;   // inverse swizzle on global source

  f32x4 acc[4][NFR];
#pragma unroll
  for (int a = 0; a < 4; a++)
#pragma unroll
    for (int b2 = 0; b2 < NFR; b2++) acc[a][b2] = (f32x4){0.f, 0.f, 0.f, 0.f};

  // prologue: stage k-step 0 into buf 0 (no drain: first-iter vmcnt covers it)
#pragma unroll
  for (int j = 0; j < 4; j++) {
    int row = (wv * 4 + j) * 8 + subrow;
    gload16(X + (size_t)(m0 + row) * K + coloff,
            (unsigned short*)(smem + (wv * 4 + j) * 1024));
  }
#pragma unroll
  for (int j = 0; j < NFR; j++) {
    int row = (wv * NFR + j) * 8 + subrow;
    gload16(W + (size_t)(n0 + row) * K + coloff,
            (unsigned short*)(smem + 16384 + (wv * NFR + j) * 1024));
  }

#pragma unroll
  for (int ks = 0; ks < 8; ks++) {
    const int buf = ks & 1;
    char* cur = smem + buf * BUF;
    if (ks < 7) {                     // issue next-tile loads first
      char* nxt = smem + (buf ^ 1) * BUF;
      int k0 = (ks + 1) * 64;
#pragma unroll
      for (int j = 0; j < 4; j++) {
        int row = (wv * 4 + j) * 8 + subrow;
        gload16(X + (size_t)(m0 + row) * K + k0 + coloff,
                (unsigned short*)(nxt + (wv * 4 + j) * 1024));
      }
#pragma unroll
      for (int j = 0; j < NFR; j++) {
        int row = (wv * NFR + j) * 8 + subrow;
        gload16(W + (size_t)(n0 + row) * K + k0 + coloff,
                (unsigned short*)(nxt + 16384 + (wv * NFR + j) * 1024));
      }
      // counted wait: only tile-ks loads (oldest) must land; next tile's stay in flight
      if constexpr (NFR == 4) asm volatile("s_waitcnt vmcnt(8)" ::: "memory");
      else if constexpr (NFR == 2) asm volatile("s_waitcnt vmcnt(6)" ::: "memory");
      else asm volatile("s_waitcnt vmcnt(5)" ::: "memory");
    } else {
      asm volatile("s_waitcnt vmcnt(0)" ::: "memory");
    }
    __builtin_amdgcn_s_barrier();          // all waves' tile-ks data visible
    __builtin_amdgcn_sched_barrier(0);

#pragma unroll
    for (int s = 0; s < 2; s++) {
      bf16x8 af[4], bfr[NFR];
#pragma unroll
      for (int mt = 0; mt < 4; mt++) {
        int row = wm + 16 * mt + li;
        af[mt] = *(const bf16x8*)(cur + (row * 8 + ((g + 4 * s) ^ (row & 7))) * 16);
      }
#pragma unroll
      for (int nt = 0; nt < NFR; nt++) {
        int row = wn + 16 * nt + li;
        bfr[nt] = *(const bf16x8*)(cur + 16384 +
                                   (row * 8 + ((g + 4 * s) ^ (row & 7))) * 16);
      }
#pragma unroll
      for (int mt = 0; mt < 4; mt++)
#pragma unroll
        for (int nt = 0; nt < NFR; nt++)
          acc[mt][nt] = __builtin_amdgcn_mfma_f32_16x16x32_bf16(
              af[mt], bfr[nt], acc[mt][nt], 0, 0, 0);
    }
    if (ks < 7) bar_only();                // guard buffer overwrite by iter ks+1's issues
  }

  float bv[NFR];
#pragma unroll
  for (int nt = 0; nt < NFR; nt++) bv[nt] = bias[n0 + wn + 16 * nt + li];

  if (VOUT && n0 >= 1024) {
    // transposed V output: LDS bounce (rows = tile cols, stride 136 shorts)
    unsigned short* Ts = (unsigned short*)smem;
    __builtin_amdgcn_s_barrier();          // all compute reads of smem done
#pragma unroll
    for (int nt = 0; nt < NFR; nt++) {
      int col = wn + 16 * nt + li;
      float bvn = bv[nt];
#pragma unroll
      for (int mt = 0; mt < 4; mt++) {
        float v0 = acc[mt][nt][0] + bvn, v1 = acc[mt][nt][1] + bvn;
        float v2 = acc[mt][nt][2] + bvn, v3 = acc[mt][nt][3] + bvn;
        uint2 pk;
        asm("v_cvt_pk_bf16_f32 %0, %1, %2" : "=v"(pk.x) : "v"(v0), "v"(v1));
        asm("v_cvt_pk_bf16_f32 %0, %1, %2" : "=v"(pk.y) : "v"(v2), "v"(v3));
        *(uint2*)(Ts + col * 136 + wm + 16 * mt + 4 * g) = pk;
      }
    }
    __syncthreads();
    int vcol = t >> 1, half = t & 1;
    int gc = n0 - 1024 + vcol;
    int bh = (m0 >> 11) * 8 + (gc >> 6);
    int d  = gc & 63;
    unsigned short* dst = VT + ((size_t)bh * 64 + d) * 2048 + (m0 & 2047) + half * 64;
    const unsigned short* srcp = Ts + vcol * 136 + half * 64;
#pragma unroll
    for (int j2 = 0; j2 < 8; j2++)
      *(bf16x8*)(dst + j2 * 8) = *(const bf16x8*)(srcp + j2 * 8);
    return;
  }

#pragma unroll
  for (int mt = 0; mt < 4; mt++) {
#pragma unroll
    for (int i = 0; i < 4; i++) {
      size_t roff = (size_t)(m0 + wm + 16 * mt + 4 * g + i) * N;
#pragma unroll
      for (int nt = 0; nt < NFR; nt++) {
        int col = n0 + wn + 16 * nt + li;
        float v = acc[mt][nt][i] + bv[nt];
        if (EPI == 1) {
          v += bf2f(R[roff + col]);
          Yb[roff + col] = f2bf(v);
        } else if (EPI == 2) {
          v = v / (1.f + __expf(-v));
          Yb[roff + col] = f2bf(v);
        } else if (EPI == 3) {
          Yf[roff + col] = v;
        } else {
          if (QSCALE && col < 512) v *= 0.18033688011112042f;  // 0.125*log2(e)
          Yb[roff + col] = f2bf(v);
        }
      }
    }
  }
}

// ---------------- MFMA flash attention, 2-phase pipelined, KVBLK=128 ----------
// QBLK=128; grid 512: bh = bid&31 (XCD-local), qi = bid>>5; 4 waves.
// Q prescaled by 0.125*log2(e); softmax is NO-MAX: p = 2^s directly.
__global__ __launch_bounds__(256) void attn_mfma(
    const unsigned short* __restrict__ qkv,  // [8192,1536] bf16
    const unsigned short* __restrict__ Vt,   // [32,64,2048] bf16
    unsigned short* __restrict__ ctx)        // [8192,512] bf16
{
  const int L = 2048;
  int bh = blockIdx.x & 31, qi = blockIdx.x >> 5;   // same-bh blocks -> same XCD
  int b = bh >> 3, h = bh & 7;
  int q0 = qi << 7;
  size_t tb = (size_t)b * L;
  int t = threadIdx.x, lane = t & 63, wv = t >> 6;
  int g = lane >> 4, li = lane & 15;
  int lisw = li & 7;

  // smem: buf{0,1}: [K 16K | V 16K] at 0/32768 ; P 16K at 65536 (4K/wave)
  __shared__ __align__(16) char smem[81920];

  int wq = q0 + wv * 32;
  bf16x8 qf00, qf01, qf10, qf11;
  {
    const unsigned short* qp0 = qkv + (tb + wq + li) * 1536 + h * 64 + g * 8;
    qf00 = *(const bf16x8*)qp0;
    qf01 = *(const bf16x8*)(qp0 + 32);
    const unsigned short* qp1 = qp0 + (size_t)16 * 1536;
    qf10 = *(const bf16x8*)qp1;
    qf11 = *(const bf16x8*)(qp1 + 32);
  }

  f32x4 accA[4], accB[4];
#pragma unroll
  for (int nt = 0; nt < 4; nt++) {
    accA[nt] = (f32x4){0.f, 0.f, 0.f, 0.f};
    accB[nt] = (f32x4){0.f, 0.f, 0.f, 0.f};
  }
  float lA = 0.f, lB = 0.f;

  // K fragment offsets (K region rows = 128B): row = 16mt+li
  int koff0 = li * 128 + ((g    ) ^ lisw) * 16;
  int koff1 = li * 128 + ((g + 4) ^ lisw) * 16;
  // V fragment offsets (V region rows = 256B, 16 slots): row = 16nt+li
  int vrowb = 16384 + li * 256;
  int vs00 = ((g    ) ^ lisw) << 4;     // pass 0, d-half 0
  int vs01 = ((g + 4) ^ lisw) << 4;     // pass 0, d-half 1
  int vs10 = ((8 + g) ^ lisw) << 4;     // pass 1, d-half 0
  int vs11 = ((12 + g) ^ lisw) << 4;    // pass 1, d-half 1
  // P pointers (wave-private 4KB at 65536)
  const char* pb0 = smem + 65536 + wv * 4096 + li * 128 + ((g    ) ^ lisw) * 16;
  const char* pb1 = smem + 65536 + wv * 4096 + li * 128 + ((g + 4) ^ lisw) * 16;
  char* pwbase = smem + 65536 + wv * 4096 + li * 128 + ((g & 1) << 3);
  char* pw0 = pwbase + (((0 + (g >> 1)) ^ lisw) << 4);
  char* pw1 = pwbase + (((2 + (g >> 1)) ^ lisw) << 4);
  char* pw2 = pwbase + (((4 + (g >> 1)) ^ lisw) << 4);
  char* pw3 = pwbase + (((6 + (g >> 1)) ^ lisw) << 4);

  // staging pointers: K 4 issues (rows 0..127), V 4 issues (rows 0..63)
  int subrow = lane >> 3;
  int coloff = ((lane & 7) ^ subrow) << 3;
  const unsigned short* kp[4];
  const unsigned short* vp[4];
#pragma unroll
  for (int j = 0; j < 4; j++) {
    int krow = (wv * 4 + j) * 8 + subrow;
    kp[j] = qkv + (tb + krow) * 1536 + 512 + h * 64 + coloff;
    int vrow = (wv * 4 + j) * 4 + g;
    vp[j] = Vt + ((size_t)bh * 64 + vrow) * 2048 + ((li ^ (vrow & 7)) << 3);
  }

  // prologue: stage tile 0 into buf 0
#pragma unroll
  for (int j = 0; j < 4; j++) {
    gload16(kp[j], (unsigned short*)(smem + (wv * 4 + j) * 1024));
    gload16(vp[j], (unsigned short*)(smem + 16384 + (wv * 4 + j) * 1024));
    kp[j] += (size_t)128 * 1536; vp[j] += 128;
  }
  pipe_sync();

#pragma unroll 2
  for (int it = 0; it < 16; it++) {
    const int buf = it & 1;
    const char* base = smem + buf * 32768;
    if (it < 15) {                    // issue next tile first (latency hides)
      char* nb = smem + (buf ^ 1) * 32768;
#pragma unroll
      for (int j = 0; j < 4; j++) {
        gload16(kp[j], (unsigned short*)(nb + (wv * 4 + j) * 1024));
        gload16(vp[j], (unsigned short*)(nb + 16384 + (wv * 4 + j) * 1024));
        kp[j] += (size_t)128 * 1536; vp[j] += 128;
      }
    }

    // S^T = K . Q^T over 128 keys (8 fragments per d-half)
    f32x4 sA[8], sB[8];
#pragma unroll
    for (int mt = 0; mt < 8; mt++) {
      sA[mt] = (f32x4){0.f, 0.f, 0.f, 0.f};
      sB[mt] = (f32x4){0.f, 0.f, 0.f, 0.f};
    }
    __builtin_amdgcn_s_setprio(1);
#pragma unroll
    for (int mt = 0; mt < 8; mt++) {
      bf16x8 kf = *(const bf16x8*)(base + koff0 + mt * 2048);
      sA[mt] = __builtin_amdgcn_mfma_f32_16x16x32_bf16(kf, qf00, sA[mt], 0, 0, 0);
      sB[mt] = __builtin_amdgcn_mfma_f32_16x16x32_bf16(kf, qf10, sB[mt], 0, 0, 0);
    }
#pragma unroll
    for (int mt = 0; mt < 8; mt++) {
      bf16x8 kf = *(const bf16x8*)(base + koff1 + mt * 2048);
      sA[mt] = __builtin_amdgcn_mfma_f32_16x16x32_bf16(kf, qf01, sA[mt], 0, 0, 0);
      sB[mt] = __builtin_amdgcn_mfma_f32_16x16x32_bf16(kf, qf11, sB[mt], 0, 0, 0);
    }
    __builtin_amdgcn_s_setprio(0);

    // NO-MAX softmax: p = 2^s directly; accumulate row-sum l
    float psA = 0.f, psB = 0.f;
#define PBLK(SARR, PS, PWP, OFF)                                              \
    {                                                                         \
      float p0 = SARR[0], p1 = SARR[1], p2 = SARR[2], p3 = SARR[3];           \
      asm volatile("v_exp_f32 %0, %0\n\tv_exp_f32 %1, %1\n\t"                 \
                   "v_exp_f32 %2, %2\n\tv_exp_f32 %3, %3\n\ts_nop 1"          \
                   : "+v"(p0), "+v"(p1), "+v"(p2), "+v"(p3));                 \
      PS += (p0 + p1) + (p2 + p3);                                            \
      uint2 pv;                                                               \
      asm("v_cvt_pk_bf16_f32 %0, %1, %2" : "=v"(pv.x) : "v"(p0), "v"(p1));    \
      asm("v_cvt_pk_bf16_f32 %0, %1, %2" : "=v"(pv.y) : "v"(p2), "v"(p3));    \
      *(uint2*)(PWP + OFF) = pv;                                              \
    }
    // ---- pass 0: keys 0..63 ----
    PBLK(sA[0], psA, pw0, 0) PBLK(sA[1], psA, pw1, 0)
    PBLK(sA[2], psA, pw2, 0) PBLK(sA[3], psA, pw3, 0)
    PBLK(sB[0], psB, pw0, 2048) PBLK(sB[1], psB, pw1, 2048)
    PBLK(sB[2], psB, pw2, 2048) PBLK(sB[3], psB, pw3, 2048)
    {
      bf16x8 paA0 = *(const bf16x8*)(pb0);
      bf16x8 paB0 = *(const bf16x8*)(pb0 + 2048);
      __builtin_amdgcn_s_setprio(1);
#pragma unroll
      for (int nt = 0; nt < 4; nt++) {
        bf16x8 vb = *(const bf16x8*)(base + vrowb + nt * 4096 + vs00);
        accA[nt] = __builtin_amdgcn_mfma_f32_16x16x32_bf16(paA0, vb, accA[nt], 0, 0, 0);
        accB[nt] = __builtin_amdgcn_mfma_f32_16x16x32_bf16(paB0, vb, accB[nt], 0, 0, 0);
      }
      __builtin_amdgcn_s_setprio(0);
      bf16x8 paA1 = *(const bf16x8*)(pb1);
      bf16x8 paB1 = *(const bf16x8*)(pb1 + 2048);
      __builtin_amdgcn_s_setprio(1);
#pragma unroll
      for (int nt = 0; nt < 4; nt++) {
        bf16x8 vb = *(const bf16x8*)(base + vrowb + nt * 4096 + vs01);
        accA[nt] = __builtin_amdgcn_mfma_f32_16x16x32_bf16(paA1, vb, accA[nt], 0, 0, 0);
        accB[nt] = __builtin_amdgcn_mfma_f32_16x16x32_bf16(paB1, vb, accB[nt], 0, 0, 0);
      }
      __builtin_amdgcn_s_setprio(0);
    }
    // ---- pass 1: keys 64..127 (reuse wave-private P buffer) ----
    PBLK(sA[4], psA, pw0, 0) PBLK(sA[5], psA, pw1, 0)
    PBLK(sA[6], psA, pw2, 0) PBLK(sA[7], psA, pw3, 0)
    PBLK(sB[4], psB, pw0, 2048) PBLK(sB[5], psB, pw1, 2048)
    PBLK(sB[6], psB, pw2, 2048) PBLK(sB[7], psB, pw3, 2048)
#undef PBLK
    {
      bf16x8 paA0 = *(const bf16x8*)(pb0);
      bf16x8 paB0 = *(const bf16x8*)(pb0 + 2048);
      __builtin_amdgcn_s_setprio(1);
#pragma unroll
      for (int nt = 0; nt < 4; nt++) {
        bf16x8 vb = *(const bf16x8*)(base + vrowb + nt * 4096 + vs10);
        accA[nt] = __builtin_amdgcn_mfma_f32_16x16x32_bf16(paA0, vb, accA[nt], 0, 0, 0);
        accB[nt] = __builtin_amdgcn_mfma_f32_16x16x32_bf16(paB0, vb, accB[nt], 0, 0, 0);
      }
      __builtin_amdgcn_s_setprio(0);
      bf16x8 paA1 = *(const bf16x8*)(pb1);
      bf16x8 paB1 = *(const bf16x8*)(pb1 + 2048);
      __builtin_amdgcn_s_setprio(1);
#pragma unroll
      for (int nt = 0; nt < 4; nt++) {
        bf16x8 vb = *(const bf16x8*)(base + vrowb + nt * 4096 + vs11);
        accA[nt] = __builtin_amdgcn_mfma_f32_16x16x32_bf16(paA1, vb, accA[nt], 0, 0, 0);
        accB[nt] = __builtin_amdgcn_mfma_f32_16x16x32_bf16(paB1, vb, accB[nt], 0, 0, 0);
      }
      __builtin_amdgcn_s_setprio(0);
    }
    psA += swz16f(psA); psA += __shfl_xor(psA, 32); lA += psA;
    psB += swz16f(psB); psB += __shfl_xor(psB, 32); lB += psB;

    pipe_sync();
  }

  float liA[4], liB[4];
#pragma unroll
  for (int i = 0; i < 4; i++) {
    liA[i] = 1.f / __shfl(lA, 4 * g + i);
    liB[i] = 1.f / __shfl(lB, 4 * g + i);
  }
#pragma unroll
  for (int i = 0; i < 4; i++) {
    size_t ra = (tb + wq + 4 * g + i) * 512 + h * 64;
    size_t rb = (tb + wq + 16 + 4 * g + i) * 512 + h * 64;
#pragma unroll
    for (int nt = 0; nt < 4; nt++) {
      ctx[ra + 16 * nt + li] = f2bf(accA[nt][i] * liA[i]);
      ctx[rb + 16 * nt + li] = f2bf(accB[nt][i] * liB[i]);
    }
  }
}

// ---------------- LayerNorm over E=512 (bf16 in, bf16 out); one wave/row -----
__global__ __launch_bounds__(256) void ln_kernel(
    const unsigned short* __restrict__ X, const float* __restrict__ g,
    const float* __restrict__ b, unsigned short* __restrict__ Yb)
{
  int t = threadIdx.x, lane = t & 63, wv = t >> 6;
  size_t row = (size_t)blockIdx.x * 4 + wv;
  bf16x8 xv = *(const bf16x8*)(X + row * 512 + lane * 8);
  float xf[8];
#pragma unroll
  for (int j = 0; j < 8; j++) xf[j] = bf2f((unsigned short)xv[j]);
  float sum = 0.f, sq = 0.f;
#pragma unroll
  for (int j = 0; j < 8; j++) { sum += xf[j]; sq += xf[j] * xf[j]; }
#pragma unroll
  for (int off = 32; off > 0; off >>= 1) {
    sum += __shfl_xor(sum, off);
    sq  += __shfl_xor(sq, off);
  }
  float mu  = sum * (1.0f / 512.0f);
  float inv = rsqrtf(sq * (1.0f / 512.0f) - mu * mu + 1e-5f);
  float4 g0 = *(const float4*)(g + lane * 8);
  float4 g1 = *(const float4*)(g + lane * 8 + 4);
  float4 b0 = *(const float4*)(b + lane * 8);
  float4 b1 = *(const float4*)(b + lane * 8 + 4);
  float gw[8] = {g0.x, g0.y, g0.z, g0.w, g1.x, g1.y, g1.z, g1.w};
  float bw[8] = {b0.x, b0.y, b0.z, b0.w, b1.x, b1.y, b1.z, b1.w};
  bf16x8 yb;
#pragma unroll
  for (int j = 0; j < 8; j++)
    yb[j] = (short)f2bf((xf[j] - mu) * inv * gw[j] + bw[j]);
  *(bf16x8*)(Yb + row * 512 + lane * 8) = yb;
}

extern "C" void kernel_launch(void* const* d_in, const int* in_sizes, int n_in,
                              void* d_out, int out_size, void* d_ws, size_t ws_size,
                              hipStream_t stream) {
  (void)in_sizes; (void)n_in; (void)out_size; (void)ws_size;
  const float* x      = (const float*)d_in[0];
  const float* conv_w = (const float*)d_in[1];
  const float* conv_b = (const float*)d_in[2];
  const float* qkv_w  = (const float*)d_in[3];
  const float* qkv_b  = (const float*)d_in[4];
  const float* out_w  = (const float*)d_in[5];
  const float* out_b  = (const float*)d_in[6];
  const float* fc1_w  = (const float*)d_in[7];
  const float* fc1_b  = (const float*)d_in[8];
  const float* fc2_w  = (const float*)d_in[9];
  const float* fc2_b  = (const float*)d_in[10];
  const float* ln1_w  = (const float*)d_in[11];
  const float* ln1_b  = (const float*)d_in[12];
  const float* ln2_w  = (const float*)d_in[13];
  const float* ln2_b  = (const float*)d_in[14];
  const float* outp_w = (const float*)d_in[15];
  const float* outp_b = (const float*)d_in[16];
  float* out = (float*)d_out;

  char* p = (char*)d_ws;
  unsigned short* A    = (unsigned short*)p;            p += (size_t)8192 * 512 * 2;
  unsigned short* QKV  = (unsigned short*)p;            p += (size_t)8192 * 1536 * 2;
  unsigned short* VT   = (unsigned short*)p;            p += (size_t)32 * 64 * 2048 * 2;
  unsigned short* CTX  = (unsigned short*)p;            p += (size_t)8192 * 512 * 2;
  unsigned short* Wq   = (unsigned short*)p;            p += (size_t)4 * 1536 * 512 * 2;
  unsigned short* Wo   = (unsigned short*)p;            p += (size_t)4 * 512 * 512 * 2;
  unsigned short* W1   = (unsigned short*)p;            p += (size_t)4 * 512 * 512 * 2;
  unsigned short* W2   = (unsigned short*)p;            p += (size_t)4 * 512 * 512 * 2;
  unsigned short* Wp   = (unsigned short*)p;            p += (size_t)32 * 512 * 2;
  unsigned short* D = QKV;   // aliased: D[8192,512] bf16 in QKV region (disjoint lifetime)

  cvt_all<<<6160, 256, 0, stream>>>(qkv_w, out_w, fc1_w, fc2_w, outp_w, Wq);

  conv_pe_kernel<<<1024, 256, 0, stream>>>(x, conv_w, conv_b, A);

  for (int l = 0; l < 4; l++) {
    gemm_bf<0, 1, 4, 1><<<64 * 12, 256, 0, stream>>>(
        A, Wq + (size_t)l * 1536 * 512, qkv_b + l * 1536, nullptr,
        QKV, nullptr, VT, 1536);
    attn_mfma<<<512, 256, 0, stream>>>(QKV, VT, CTX);
    gemm_bf<1, 0, 2, 0><<<64 * 8, 256, 0, stream>>>(
        CTX, Wo + (size_t)l * 512 * 512, out_b + l * 512, A,
        D, nullptr, nullptr, 512);
    ln_kernel<<<2048, 256, 0, stream>>>(D, ln1_w + l * 512, ln1_b + l * 512, A);
    gemm_bf<2, 0, 2, 0><<<64 * 8, 256, 0, stream>>>(
        A, W1 + (size_t)l * 512 * 512, fc1_b + l * 512, nullptr,
        CTX, nullptr, nullptr, 512);
    gemm_bf<1, 0, 2, 0><<<64 * 8, 256, 0, stream>>>(
        CTX, W2 + (size_t)l * 512 * 512, fc2_b + l * 512, A,
        D, nullptr, nullptr, 512);
    ln_kernel<<<2048, 256, 0, stream>>>(D, ln2_w + l * 512, ln2_b + l * 512, A);
  }
  gemm_bf<3, 0, 1, 0><<<64, 256, 0, stream>>>(
      A, Wp, outp_b, nullptr, nullptr, out, nullptr, 32);
}